// Round 7
// baseline (674.375 us; speedup 1.0000x reference)
//
#include <hip/hip_runtime.h>

#define NN 50000
#define NE 800000
#define FF 128
#define KF 8
#define DD 16
#define GG 512
#define BN_EPS 1e-5f
#define NB 196   // ceil(NN/256)
#define KSTR 264 // padded k-block stride for block-diag weights (flat staging)
#define BSTR 20  // padded per-16-col block stride (floats) in aggbd As/Ts: banks k*20%32 all-distinct

using s8v = __attribute__((ext_vector_type(8))) short;
using f4v = __attribute__((ext_vector_type(4))) float;
using h4v = __attribute__((ext_vector_type(4))) _Float16;
using h8v = __attribute__((ext_vector_type(8))) _Float16;
typedef unsigned int u32;

// async global->LDS, 16B per lane; LDS dest = wave-uniform base + lane*16 (m104),
// global src is PER-LANE (m173) -> swizzled layouts via pre-swizzled source address.
__device__ __forceinline__ void gload_lds16(const void* g, void* l) {
    __builtin_amdgcn_global_load_lds((const __attribute__((address_space(1))) u32*)g,
                                     (__attribute__((address_space(3))) u32*)l, 16, 0, 0);
}

// ---------------- CSR build ----------------
__global__ void k_deg(const int* __restrict__ dst, int* __restrict__ deg) {
    int e = blockIdx.x * 256 + threadIdx.x;
    if (e < NE) atomicAdd(&deg[dst[e]], 1);
}

__global__ __launch_bounds__(256) void k_bsum(const int* __restrict__ deg, int* __restrict__ bsum) {
    int idx = blockIdx.x * 256 + threadIdx.x;
    int v = (idx < NN) ? deg[idx] : 0;
#pragma unroll
    for (int off = 32; off; off >>= 1) v += __shfl_down(v, off, 64);
    __shared__ int ws[4];
    if ((threadIdx.x & 63) == 0) ws[threadIdx.x >> 6] = v;
    __syncthreads();
    if (threadIdx.x == 0) bsum[blockIdx.x] = ws[0] + ws[1] + ws[2] + ws[3];
}

__global__ __launch_bounds__(256) void k_bscan(const int* __restrict__ bsum, int* __restrict__ boffs) {
    __shared__ int s[256];
    int tid = threadIdx.x;
    int v = (tid < NB) ? bsum[tid] : 0;
    s[tid] = v;
    __syncthreads();
    for (int off = 1; off < 256; off <<= 1) {
        int t = (tid >= off) ? s[tid - off] : 0;
        __syncthreads();
        s[tid] += t;
        __syncthreads();
    }
    if (tid < NB) boffs[tid] = s[tid] - v;  // exclusive
}

__global__ __launch_bounds__(256) void k_offs(const int* __restrict__ deg,
                                              const int* __restrict__ boffs,
                                              int* __restrict__ offs) {
    __shared__ int s[256];
    int tid = threadIdx.x;
    int idx = blockIdx.x * 256 + tid;
    int v = (idx < NN) ? deg[idx] : 0;
    s[tid] = v;
    __syncthreads();
    for (int off = 1; off < 256; off <<= 1) {
        int t = (tid >= off) ? s[tid - off] : 0;
        __syncthreads();
        s[tid] += t;
        __syncthreads();
    }
    int incl = s[tid];
    if (idx < NN) offs[idx] = boffs[blockIdx.x] + incl - v;
    if (idx == NN - 1) offs[NN] = boffs[blockIdx.x] + incl;
}

__global__ void k_fill(const int* __restrict__ src, const int* __restrict__ dst,
                       const int* __restrict__ offs, int* __restrict__ cnt,
                       int* __restrict__ csr) {
    int e = blockIdx.x * 256 + threadIdx.x;
    if (e < NE) {
        int d = dst[e];
        int p = atomicAdd(&cnt[d], 1);
        csr[offs[d] + p] = src[e];
    }
}

// ---------------- helpers ----------------
// split fp32 -> bf16 hi + bf16 lo (round-to-nearest-even both)
__device__ __forceinline__ void f2bf2(float v, unsigned short& hi, unsigned short& lo) {
    unsigned u = __float_as_uint(v);
    unsigned r = u + 0x7fffu + ((u >> 16) & 1u);
    hi = (unsigned short)(r >> 16);
    float hf = __uint_as_float(((unsigned)hi) << 16);
    float lf = v - hf;
    unsigned u2 = __float_as_uint(lf);
    unsigned r2 = u2 + 0x7fffu + ((u2 >> 16) & 1u);
    lo = (unsigned short)(r2 >> 16);
}

// ---------------- fp32 -> fp16 one-shot convert of the input x ----------------
__global__ __launch_bounds__(256) void k_cvt(const float4* __restrict__ X, h4v* __restrict__ O) {
    int i = blockIdx.x * 256 + threadIdx.x;  // over NN*32
    if (i < NN * 32) {
        float4 v = X[i];
        h4v o;
        o.x = (_Float16)v.x; o.y = (_Float16)v.y;
        o.z = (_Float16)v.z; o.w = (_Float16)v.w;
        O[i] = o;
    }
}

// ---------------- weight prep: fp32 [l][k][n] -> bf16 hi/lo transposed [n][k] -------
__global__ __launch_bounds__(256) void k_wprep(const float* __restrict__ W1,
                                               const float* __restrict__ W2,
                                               unsigned short* __restrict__ out) {
    int idx = blockIdx.x * 256 + threadIdx.x;  // over 3*2*16384
    if (idx >= 3 * 2 * 16384) return;
    int l = idx / (2 * 16384);
    int rem = idx % (2 * 16384);
    int mat = rem >> 14;
    int e = rem & 16383;
    int n = e >> 7, k = e & 127;
    const float* W = (mat == 0) ? (W1 + (size_t)l * 16384) : (W2 + (size_t)l * 16384);
    float v = W[k * 128 + n];
    unsigned short hi, lo;
    f2bf2(v, hi, lo);
    unsigned short* o = out + (size_t)((l * 2 + mat) * 2) * 16384;
    o[n * 128 + k] = hi;
    o[16384 + n * 128 + k] = lo;
}

// ---------------- weight prep for h0: Wcat^T (slot 6) + blockdiag(W2)^T (slot 7) ---
__global__ __launch_bounds__(256) void k_wprep_h0(const float* __restrict__ W1,  // [K,F,d]
                                                  const float* __restrict__ W2,  // [K,d,d]
                                                  unsigned short* __restrict__ out) {
    int idx = blockIdx.x * 256 + threadIdx.x;  // over 2*16384
    if (idx >= 2 * 16384) return;
    int mat = idx >> 14;
    int e = idx & 16383;
    int n = e >> 7, k = e & 127;
    float v;
    if (mat == 0) {
        v = W1[(n >> 4) * (FF * DD) + k * DD + (n & 15)];
    } else {
        v = ((k >> 4) == (n >> 4)) ? W2[(n >> 4) * 256 + (k & 15) * DD + (n & 15)] : 0.f;
    }
    unsigned short hi, lo;
    f2bf2(v, hi, lo);
    unsigned short* o = out + (size_t)(6 + mat) * 32768;
    o[n * 128 + k] = hi;
    o[16384 + n * 128 + k] = lo;
}

// ---------------- aggregation: paired-edge 16B gather ----------------
// R7: 32-lane group, each 16B load covers TWO edges (lanes 0-15 edge e, 16-31 edge e+1;
// 8 features/lane). 8 unrolled loads = 16 edges in flight (2x R6's parallelism, half the
// load instrs). Cross-half merge: 8x shfl_xor(16) once per node. fp32 BN/relu/acc as before.
template <bool BN, bool RELU>
__global__ __launch_bounds__(256) void k_agg(const h4v* __restrict__ X,
                                             const int* __restrict__ offs,
                                             const int* __restrict__ csr,
                                             const float* __restrict__ st,
                                             const float* __restrict__ g,
                                             const float* __restrict__ be,
                                             unsigned short* __restrict__ Zhi,
                                             unsigned short* __restrict__ Zlo) {
    const char* Xb = (const char*)X;  // rows of 256B
    int grp = threadIdx.x >> 5;
    int lane = threadIdx.x & 31;
    int half = lane >> 4;
    int l16 = lane & 15;
    int n = blockIdx.x * 8 + grp;

    float a8[8], b8[8];
    if (BN) {
        const float inv_n = 1.0f / (float)NN;
#pragma unroll
        for (int t = 0; t < 8; t++) {
            int c = l16 * 8 + t;
            float mu = st[c] * inv_n;
            float var = st[FF + c] * inv_n - mu * mu;
            float a = g[c] * rsqrtf(var + BN_EPS);
            a8[t] = a;
            b8[t] = be[c] - mu * a;
        }
    }

    float acc[8];
#pragma unroll
    for (int t = 0; t < 8; t++) acc[t] = 0.f;

    auto accum = [&](h8v v) {
#pragma unroll
        for (int t = 0; t < 8; t++) {
            float f = (float)v[t];
            if (BN) f = fmaf(f, a8[t], b8[t]);
            if (RELU) f = fmaxf(f, 0.f);
            acc[t] += f;
        }
    };

    if (half == 0) accum(*(const h8v*)(Xb + (size_t)n * 256 + l16 * 16));

    int e0 = offs[n], e1 = offs[n + 1];
    int e = e0;
    for (; e + 16 <= e1; e += 16) {
        int s0 = csr[e + 0 + half], s1 = csr[e + 2 + half];
        int s2 = csr[e + 4 + half], s3 = csr[e + 6 + half];
        int s4 = csr[e + 8 + half], s5 = csr[e + 10 + half];
        int s6 = csr[e + 12 + half], s7 = csr[e + 14 + half];
        h8v v0 = *(const h8v*)(Xb + (size_t)s0 * 256 + l16 * 16);
        h8v v1 = *(const h8v*)(Xb + (size_t)s1 * 256 + l16 * 16);
        h8v v2 = *(const h8v*)(Xb + (size_t)s2 * 256 + l16 * 16);
        h8v v3 = *(const h8v*)(Xb + (size_t)s3 * 256 + l16 * 16);
        h8v v4 = *(const h8v*)(Xb + (size_t)s4 * 256 + l16 * 16);
        h8v v5 = *(const h8v*)(Xb + (size_t)s5 * 256 + l16 * 16);
        h8v v6 = *(const h8v*)(Xb + (size_t)s6 * 256 + l16 * 16);
        h8v v7 = *(const h8v*)(Xb + (size_t)s7 * 256 + l16 * 16);
        accum(v0); accum(v1); accum(v2); accum(v3);
        accum(v4); accum(v5); accum(v6); accum(v7);
    }
    for (; e + 8 <= e1; e += 8) {
        int s0 = csr[e + 0 + half], s1 = csr[e + 2 + half];
        int s2 = csr[e + 4 + half], s3 = csr[e + 6 + half];
        h8v v0 = *(const h8v*)(Xb + (size_t)s0 * 256 + l16 * 16);
        h8v v1 = *(const h8v*)(Xb + (size_t)s1 * 256 + l16 * 16);
        h8v v2 = *(const h8v*)(Xb + (size_t)s2 * 256 + l16 * 16);
        h8v v3 = *(const h8v*)(Xb + (size_t)s3 * 256 + l16 * 16);
        accum(v0); accum(v1); accum(v2); accum(v3);
    }
    for (; e + 2 <= e1; e += 2) {
        int s = csr[e + half];
        accum(*(const h8v*)(Xb + (size_t)s * 256 + l16 * 16));
    }
    if (e < e1 && half == 0) {
        int s = csr[e];
        accum(*(const h8v*)(Xb + (size_t)s * 256 + l16 * 16));
    }

#pragma unroll
    for (int t = 0; t < 8; t++) acc[t] += __shfl_xor(acc[t], 16);

    if (half == 0) {
        unsigned short h[8], l[8];
#pragma unroll
        for (int t = 0; t < 8; t++) f2bf2(acc[t], h[t], l[t]);
        *(ushort4*)&Zhi[(size_t)n * 128 + l16 * 8] = make_ushort4(h[0], h[1], h[2], h[3]);
        *(ushort4*)&Zhi[(size_t)n * 128 + l16 * 8 + 4] = make_ushort4(h[4], h[5], h[6], h[7]);
        *(ushort4*)&Zlo[(size_t)n * 128 + l16 * 8] = make_ushort4(l[0], l[1], l[2], l[3]);
        *(ushort4*)&Zlo[(size_t)n * 128 + l16 * 8 + 4] = make_ushort4(l[4], l[5], l[6], l[7]);
    }
}

// ============ MFMA bf16x3 GEMM pair (R6 gload_lds + T3 overlap, unchanged) ============
__global__ __launch_bounds__(256) void gemm_mfma(const unsigned short* __restrict__ Zhi,
                                                 const unsigned short* __restrict__ Zlo,
                                                 const unsigned short* __restrict__ W1T,
                                                 const unsigned short* __restrict__ W2T,
                                                 const float* __restrict__ b1,
                                                 const float* __restrict__ b2,
                                                 _Float16* __restrict__ C,
                                                 float* __restrict__ stout) {
    __shared__ __align__(16) unsigned short Zs[16384];   // A/z hi+lo, [p][64][256B], 32KB
    __shared__ __align__(16) unsigned short Wch[16384];  // W chunk dbuf 2 x 16KB
    __shared__ float Sred[1024];                         // 4KB stats scratch
    int tid = threadIdx.x;
    int row0 = blockIdx.x * 64;
    int w = tid >> 6, lane = tid & 63, quad = lane >> 4, lid = lane & 15;

    // ---- per-thread W-stage source offsets (shorts, sans kc) ----
    int wsrc[4], wdst[4];
#pragma unroll
    for (int i = 0; i < 4; i++) {
        int L = (w * 4 + i) * 1024 + lane * 16;  // byte within 16KB chunk image
        int p = L >> 13, r13 = L & 8191;
        int npair = r13 >> 7, cc = r13 & 127;
        int ccp = cc ^ ((npair & 7) << 4);
        wsrc[i] = p * 16384 + (npair * 2 + (ccp >> 6)) * 128 + ((ccp & 63) >> 1);
        wdst[i] = (w * 4 + i) * 1024;            // wave-uniform LDS byte base
    }

    // ---- stage A hi/lo planes into Zs (global src pre-swizzled) ----
#pragma unroll
    for (int i = 0; i < 8; i++) {
        int L = (w * 8 + i) * 1024 + lane * 16;
        int p = L >> 14, r14 = L & 16383;
        int row = r14 >> 8, cb = r14 & 255;
        int cbp = cb ^ ((row & 7) << 4);
        int grow = row0 + row;
        if (grow >= NN) grow = NN - 1;
        const unsigned short* gs = (p ? Zlo : Zhi) + (size_t)grow * 128 + (cbp >> 1);
        gload_lds16(gs, (char*)Zs + (w * 8 + i) * 1024);
    }
    // ---- stage W1 chunk 0 into buf 0 ----
#pragma unroll
    for (int i = 0; i < 4; i++)
        gload_lds16(W1T + wsrc[i], (char*)Wch + wdst[i]);
    __syncthreads();

    // ---- per-thread read-address precompute ----
    int lr = w * 16 + lid;
    int swzr = (lr & 7) << 4;
    int abase = lr * 256;  // byte within plane 0 of Zs
    int boff[8];
#pragma unroll
    for (int n0 = 0; n0 < 8; n0++) {
        int nn = n0 * 16 + lid;
        int cc = ((nn & 1) << 6) | (quad << 4);
        boff[n0] = (nn >> 1) * 128 + (cc ^ (((nn >> 1) & 7) << 4));
    }

    f4v acc[8];
#pragma unroll
    for (int i = 0; i < 8; i++) acc[i] = 0;

    // ---- unified 8-chunk loop: g 0..3 = phase 1 (W1), 4..7 = phase 2 (W2) ----
    for (int g = 0; g < 8; ++g) {
        int buf = g & 1;
        if (g < 7) {  // issue next chunk's stage first (overlaps with compute below)
            const unsigned short* WT = (g + 1 < 4) ? W1T : W2T;
            int kcn = (g + 1) & 3;
#pragma unroll
            for (int i = 0; i < 4; i++)
                gload_lds16(WT + wsrc[i] + kcn * 32,
                            (char*)Wch + (buf ^ 1) * 16384 + wdst[i]);
        }
        int kc = g & 3;
        int aoff = (kc * 64 + quad * 16) ^ swzr;
        s8v ah = *(const s8v*)((const char*)Zs + abase + aoff);
        s8v al = *(const s8v*)((const char*)Zs + 16384 + abase + aoff);
        const char* wb = (const char*)Wch + buf * 16384;
#pragma unroll
        for (int n0 = 0; n0 < 8; n0++) {
            s8v bh = *(const s8v*)(wb + boff[n0]);
            s8v bl = *(const s8v*)(wb + 8192 + boff[n0]);
            acc[n0] = __builtin_amdgcn_mfma_f32_16x16x32_bf16(ah, bh, acc[n0], 0, 0, 0);
            acc[n0] = __builtin_amdgcn_mfma_f32_16x16x32_bf16(al, bh, acc[n0], 0, 0, 0);
            acc[n0] = __builtin_amdgcn_mfma_f32_16x16x32_bf16(ah, bl, acc[n0], 0, 0, 0);
        }
        if (g == 3) {
            // z = relu(acc+b1) -> overwrite Zs (wave-local rows), same swizzled layout
#pragma unroll
            for (int n0 = 0; n0 < 8; n0++) {
                int c = n0 * 16 + lid;
                float bb = b1[c];
#pragma unroll
                for (int rr = 0; rr < 4; rr++) {
                    int zr = w * 16 + quad * 4 + rr;
                    float z = fmaxf(acc[n0][rr] + bb, 0.f);
                    unsigned short h, lo2;
                    f2bf2(z, h, lo2);
                    int zb = zr * 256 + ((2 * c) ^ ((zr & 7) << 4));
                    *(unsigned short*)((char*)Zs + zb) = h;
                    *(unsigned short*)((char*)Zs + 16384 + zb) = lo2;
                }
                acc[n0] = 0;
            }
        }
        if (g < 7) __syncthreads();  // drains next-chunk stage; orders buffer reuse
    }

    // ---- epilogue: bias, fp16 store, stats (stats from fp32 register values) ----
#pragma unroll
    for (int n0 = 0; n0 < 8; n0++) {
        int c = n0 * 16 + lid;
        float bb = b2[c];
        float s = 0.f, q = 0.f;
#pragma unroll
        for (int rr = 0; rr < 4; rr++) {
            int grow = row0 + w * 16 + quad * 4 + rr;
            if (grow < NN) {
                float v = acc[n0][rr] + bb;
                C[(size_t)grow * 128 + c] = (_Float16)v;
                s += v;
                q += v * v;
            }
        }
        s += __shfl_xor(s, 16); s += __shfl_xor(s, 32);
        q += __shfl_xor(q, 16); q += __shfl_xor(q, 32);
        if (quad == 0) {
            Sred[w * 128 + c] = s;
            Sred[512 + w * 128 + c] = q;
        }
    }
    __syncthreads();
    if (tid < 128) {
        float s = Sred[tid] + Sred[128 + tid] + Sred[256 + tid] + Sred[384 + tid];
        float q = Sred[512 + tid] + Sred[640 + tid] + Sred[768 + tid] + Sred[896 + tid];
        atomicAdd(&stout[tid], s);
        atomicAdd(&stout[FF + tid], q);
    }
}

// ---------------- fused h1: paired-edge gather + double block-diag MLP -----------
__global__ __launch_bounds__(256) void k_aggbd(const h4v* __restrict__ X,
                                               const int* __restrict__ offs,
                                               const int* __restrict__ csr,
                                               const float* __restrict__ st,
                                               const float* __restrict__ g,
                                               const float* __restrict__ be,
                                               const float* __restrict__ W1,
                                               const float4* __restrict__ b1,
                                               const float* __restrict__ W2,
                                               const float4* __restrict__ b2,
                                               float4* __restrict__ C) {
    __shared__ float As[8][8 * BSTR];
    __shared__ float Ts[8][8 * BSTR];
    __shared__ float Ws1[KF * KSTR];
    __shared__ float Ws2[KF * KSTR];
    const char* Xb = (const char*)X;
    int grp = threadIdx.x >> 5, lane = threadIdx.x & 31;
    int half = lane >> 4, l16 = lane & 15;
    int n = blockIdx.x * 8 + grp;

    for (int l = threadIdx.x; l < KF * 256; l += 256) {
        int k = l >> 8, r = l & 255;
        Ws1[k * KSTR + r] = W1[l];
        Ws2[k * KSTR + r] = W2[l];
    }

    float a8[8], b8[8];
    {
        const float inv_n = 1.0f / (float)NN;
#pragma unroll
        for (int t = 0; t < 8; t++) {
            int c = l16 * 8 + t;
            float mu = st[c] * inv_n;
            float var = st[FF + c] * inv_n - mu * mu;
            float a = g[c] * rsqrtf(var + BN_EPS);
            a8[t] = a;
            b8[t] = be[c] - mu * a;
        }
    }

    float acc[8];
#pragma unroll
    for (int t = 0; t < 8; t++) acc[t] = 0.f;

    auto accum = [&](h8v v) {
#pragma unroll
        for (int t = 0; t < 8; t++) {
            float f = fmaxf(fmaf((float)v[t], a8[t], b8[t]), 0.f);
            acc[t] += f;
        }
    };

    if (half == 0) accum(*(const h8v*)(Xb + (size_t)n * 256 + l16 * 16));

    int e0 = offs[n], e1 = offs[n + 1];
    int e = e0;
    for (; e + 16 <= e1; e += 16) {
        int s0 = csr[e + 0 + half], s1 = csr[e + 2 + half];
        int s2 = csr[e + 4 + half], s3 = csr[e + 6 + half];
        int s4 = csr[e + 8 + half], s5 = csr[e + 10 + half];
        int s6 = csr[e + 12 + half], s7 = csr[e + 14 + half];
        h8v v0 = *(const h8v*)(Xb + (size_t)s0 * 256 + l16 * 16);
        h8v v1 = *(const h8v*)(Xb + (size_t)s1 * 256 + l16 * 16);
        h8v v2 = *(const h8v*)(Xb + (size_t)s2 * 256 + l16 * 16);
        h8v v3 = *(const h8v*)(Xb + (size_t)s3 * 256 + l16 * 16);
        h8v v4 = *(const h8v*)(Xb + (size_t)s4 * 256 + l16 * 16);
        h8v v5 = *(const h8v*)(Xb + (size_t)s5 * 256 + l16 * 16);
        h8v v6 = *(const h8v*)(Xb + (size_t)s6 * 256 + l16 * 16);
        h8v v7 = *(const h8v*)(Xb + (size_t)s7 * 256 + l16 * 16);
        accum(v0); accum(v1); accum(v2); accum(v3);
        accum(v4); accum(v5); accum(v6); accum(v7);
    }
    for (; e + 8 <= e1; e += 8) {
        int s0 = csr[e + 0 + half], s1 = csr[e + 2 + half];
        int s2 = csr[e + 4 + half], s3 = csr[e + 6 + half];
        h8v v0 = *(const h8v*)(Xb + (size_t)s0 * 256 + l16 * 16);
        h8v v1 = *(const h8v*)(Xb + (size_t)s1 * 256 + l16 * 16);
        h8v v2 = *(const h8v*)(Xb + (size_t)s2 * 256 + l16 * 16);
        h8v v3 = *(const h8v*)(Xb + (size_t)s3 * 256 + l16 * 16);
        accum(v0); accum(v1); accum(v2); accum(v3);
    }
    for (; e + 2 <= e1; e += 2) {
        int s = csr[e + half];
        accum(*(const h8v*)(Xb + (size_t)s * 256 + l16 * 16));
    }
    if (e < e1 && half == 0) {
        int s = csr[e];
        accum(*(const h8v*)(Xb + (size_t)s * 256 + l16 * 16));
    }

#pragma unroll
    for (int t = 0; t < 8; t++) acc[t] += __shfl_xor(acc[t], 16);

    // half-0 lanes write the same padded As layout as before: feature f = l16*8+t
    if (half == 0) {
        int kb = l16 >> 1, off = (l16 & 1) * 8;
        float4 lo4 = make_float4(acc[0], acc[1], acc[2], acc[3]);
        float4 hi4 = make_float4(acc[4], acc[5], acc[6], acc[7]);
        *(float4*)&As[grp][kb * BSTR + off] = lo4;
        *(float4*)&As[grp][kb * BSTR + off + 4] = hi4;
    }
    __syncthreads();

    int k = lane >> 2, jb = (lane & 3) * 4;
    float a[16];
    {
        const float4* As4 = (const float4*)&As[grp][k * BSTR];
        float4 a0 = As4[0], a1 = As4[1], a2 = As4[2], a3 = As4[3];
        a[0] = a0.x; a[1] = a0.y; a[2] = a0.z; a[3] = a0.w;
        a[4] = a1.x; a[5] = a1.y; a[6] = a1.z; a[7] = a1.w;
        a[8] = a2.x; a[9] = a2.y; a[10] = a2.z; a[11] = a2.w;
        a[12] = a3.x; a[13] = a3.y; a[14] = a3.z; a[15] = a3.w;
    }
    const float* wp1 = &Ws1[k * KSTR + jb];
    float4 t = b1[lane];
#pragma unroll
    for (int i = 0; i < 16; i++) {
        float4 wv = *(const float4*)&wp1[i * 16];
        t.x = fmaf(a[i], wv.x, t.x);
        t.y = fmaf(a[i], wv.y, t.y);
        t.z = fmaf(a[i], wv.z, t.z);
        t.w = fmaf(a[i], wv.w, t.w);
    }
    t.x = fmaxf(t.x, 0.f); t.y = fmaxf(t.y, 0.f);
    t.z = fmaxf(t.z, 0.f); t.w = fmaxf(t.w, 0.f);
    *(float4*)&Ts[grp][(lane >> 2) * BSTR + (lane & 3) * 4] = t;
    __syncthreads();

    float b[16];
    {
        const float4* Ts4 = (const float4*)&Ts[grp][k * BSTR];
        float4 a0 = Ts4[0], a1 = Ts4[1], a2 = Ts4[2], a3 = Ts4[3];
        b[0] = a0.x; b[1] = a0.y; b[2] = a0.z; b[3] = a0.w;
        b[4] = a1.x; b[5] = a1.y; b[6] = a1.z; b[7] = a1.w;
        b[8] = a2.x; b[9] = a2.y; b[10] = a2.z; b[11] = a2.w;
        b[12] = a3.x; b[13] = a3.y; b[14] = a3.z; b[15] = a3.w;
    }
    const float* wp2 = &Ws2[k * KSTR + jb];
    float4 acc2 = b2[lane];
#pragma unroll
    for (int i = 0; i < 16; i++) {
        float4 wv = *(const float4*)&wp2[i * 16];
        acc2.x = fmaf(b[i], wv.x, acc2.x);
        acc2.y = fmaf(b[i], wv.y, acc2.y);
        acc2.z = fmaf(b[i], wv.z, acc2.z);
        acc2.w = fmaf(b[i], wv.w, acc2.w);
    }
    C[(size_t)n * 32 + lane] = acc2;
}

// ---------------- BN stats (standalone, for k_aggbd output) ----------------
__global__ __launch_bounds__(256) void k_stats(const float* __restrict__ X,
                                               float* __restrict__ st, int nrows) {
    int c = threadIdx.x & 127;
    int half = threadIdx.x >> 7;
    int rpb = (nrows + gridDim.x - 1) / gridDim.x;
    int r0 = blockIdx.x * rpb;
    int r1 = min(r0 + rpb, nrows);
    float s = 0.f, sq = 0.f;
    for (int r = r0 + half; r < r1; r += 2) {
        float v = X[(size_t)r * FF + c];
        s += v;
        sq += v * v;
    }
    atomicAdd(&st[c], s);
    atomicAdd(&st[FF + c], sq);
}

// ---------------- pooling with fused final BN ----------------
__global__ __launch_bounds__(128) void k_pool(const float* __restrict__ X,
                                              const int* __restrict__ batch,
                                              const float* __restrict__ st,
                                              const float* __restrict__ g,
                                              const float* __restrict__ be,
                                              float* __restrict__ out) {
    int c = threadIdx.x;
    const float inv_n = 1.0f / (float)NN;
    float mu = st[c] * inv_n;
    float var = st[FF + c] * inv_n - mu * mu;
    float a = g[c] * rsqrtf(var + BN_EPS);
    float b = be[c] - mu * a;
    int chunk = (NN + gridDim.x - 1) / gridDim.x;
    int r0 = blockIdx.x * chunk;
    int r1 = min(r0 + chunk, NN);
    if (r0 >= r1) return;
    float acc = 0.f;
    int cnt = 0;
    int cur = batch[r0];
    for (int r = r0; r < r1; r++) {
        int bb = batch[r];
        if (bb != cur) {
            atomicAdd(&out[(size_t)cur * FF + c], fmaf(a, acc, b * (float)cnt));
            acc = 0.f;
            cnt = 0;
            cur = bb;
        }
        acc += X[(size_t)r * FF + c];
        cnt++;
    }
    atomicAdd(&out[(size_t)cur * FF + c], fmaf(a, acc, b * (float)cnt));
}

extern "C" void kernel_launch(void* const* d_in, const int* in_sizes, int n_in,
                              void* d_out, int out_size, void* d_ws, size_t ws_size,
                              hipStream_t stream) {
    const float* x = (const float*)d_in[0];
    const int* ei = (const int*)d_in[1];
    const int* src = ei;
    const int* dst = ei + NE;
    const int* batch = (const int*)d_in[2];
    const float* gc_W1 = (const float*)d_in[4];
    const float* gc_b1 = (const float*)d_in[5];
    const float* gc_W2 = (const float*)d_in[6];
    const float* gc_b2 = (const float*)d_in[7];
    const float* gc_g = (const float*)d_in[8];
    const float* gc_be = (const float*)d_in[9];
    const float* h0_W1 = (const float*)d_in[10];
    const float* h0_b1 = (const float*)d_in[11];
    const float* h0_W2 = (const float*)d_in[12];
    const float* h0_b2 = (const float*)d_in[13];
    const float* h0_g = (const float*)d_in[14];
    const float* h0_be = (const float*)d_in[15];
    const float* h1_W1 = (const float*)d_in[16];
    const float* h1_b1 = (const float*)d_in[17];
    const float* h1_W2 = (const float*)d_in[18];
    const float* h1_b2 = (const float*)d_in[19];
    const float* h1_g = (const float*)d_in[20];
    const float* h1_be = (const float*)d_in[21];

    const size_t NF = (size_t)NN * FF;
    float* P0 = (float*)d_ws;  // reused as two bf16 planes (Zhi, Zlo)
    float* P1 = P0 + NF;       // fp16 activation buffer (Hbuf) lives here
    float* P2 = P1 + NF;
    float* stats = P2 + NF;
    int* deg = (int*)(stats + 5 * 256);
    int* cnt = deg + NN;
    int* offs = cnt + NN;
    int* bsum = offs + (NN + 4);
    int* boffs = bsum + 256;
    int* csr = boffs + 256;
    unsigned short* wbf = (unsigned short*)(csr + NE);  // 8 slots x 32768 shorts

    unsigned short* Zhi = (unsigned short*)P0;
    unsigned short* Zlo = Zhi + NF;
    h4v* Hbuf = (h4v*)P1;  // fp16 activations, NN x 128 halves (NN*32 h4v)

    hipMemsetAsync(deg, 0, (size_t)2 * NN * sizeof(int), stream);
    hipMemsetAsync(stats, 0, 5 * 256 * sizeof(float), stream);
    hipMemsetAsync(d_out, 0, (size_t)GG * KF * DD * sizeof(float), stream);

    k_deg<<<(NE + 255) / 256, 256, 0, stream>>>(dst, deg);
    k_bsum<<<NB, 256, 0, stream>>>(deg, bsum);
    k_bscan<<<1, 256, 0, stream>>>(bsum, boffs);
    k_offs<<<NB, 256, 0, stream>>>(deg, boffs, offs);
    k_fill<<<(NE + 255) / 256, 256, 0, stream>>>(src, dst, offs, cnt, csr);
    k_wprep<<<(3 * 2 * 16384 + 255) / 256, 256, 0, stream>>>(gc_W1, gc_W2, wbf);
    k_wprep_h0<<<(2 * 16384 + 255) / 256, 256, 0, stream>>>(h0_W1, h0_W2, wbf);
    k_cvt<<<(NN * 32 + 255) / 256, 256, 0, stream>>>((const float4*)x, Hbuf);

    const int agg_grid = NN / 8;            // 6250
    const int gemm_grid = (NN + 63) / 64;   // 782

    // ---- GC layers: agg(bf16-plane out) + MFMA bf16x3 gemm pair (stats fused) ----
    k_agg<false, false><<<agg_grid, 256, 0, stream>>>(
        Hbuf, offs, csr, nullptr, nullptr, nullptr, Zhi, Zlo);
    gemm_mfma<<<gemm_grid, 256, 0, stream>>>(
        Zhi, Zlo, wbf + 0 * 32768, wbf + 1 * 32768, gc_b1, gc_b2, (_Float16*)Hbuf, stats);

    k_agg<true, true><<<agg_grid, 256, 0, stream>>>(
        Hbuf, offs, csr, stats, gc_g, gc_be, Zhi, Zlo);
    gemm_mfma<<<gemm_grid, 256, 0, stream>>>(
        Zhi, Zlo, wbf + 2 * 32768, wbf + 3 * 32768, gc_b1 + FF, gc_b2 + FF, (_Float16*)Hbuf,
        stats + 256);

    k_agg<true, true><<<agg_grid, 256, 0, stream>>>(
        Hbuf, offs, csr, stats + 256, gc_g + FF, gc_be + FF, Zhi, Zlo);
    gemm_mfma<<<gemm_grid, 256, 0, stream>>>(
        Zhi, Zlo, wbf + 4 * 32768, wbf + 5 * 32768, gc_b1 + 2 * FF, gc_b2 + 2 * FF,
        (_Float16*)Hbuf, stats + 512);

    // ---- head layer 0: agg (GC2 BN, no relu) + MFMA (Wcat + blockdiag) ----
    k_agg<true, false><<<agg_grid, 256, 0, stream>>>(
        Hbuf, offs, csr, stats + 512, gc_g + 2 * FF, gc_be + 2 * FF, Zhi, Zlo);
    gemm_mfma<<<gemm_grid, 256, 0, stream>>>(
        Zhi, Zlo, wbf + 6 * 32768, wbf + 7 * 32768, h0_b1, h0_b2, (_Float16*)Hbuf, stats + 768);

    // ---- head layer 1: fused agg(BN+relu) + double block-diag MLP ----
    k_aggbd<<<agg_grid, 256, 0, stream>>>(
        Hbuf, offs, csr, stats + 768, h0_g, h0_be,
        h1_W1, (const float4*)h1_b1, h1_W2, (const float4*)h1_b2, (float4*)P2);
    k_stats<<<256, 256, 0, stream>>>(P2, stats + 1024, NN);

    // ---- pool with fused final BN ----
    k_pool<<<512, 128, 0, stream>>>(P2, batch, stats + 1024, h1_g, h1_be, (float*)d_out);
}

// Round 8
// 618.515 us; speedup vs baseline: 1.0903x; 1.0903x over previous
//
#include <hip/hip_runtime.h>

#define NN 50000
#define NE 800000
#define FF 128
#define KF 8
#define DD 16
#define GG 512
#define BN_EPS 1e-5f
#define NB 196   // ceil(NN/256)
#define KSTR 264 // padded k-block stride for block-diag weights (flat staging)
#define BSTR 20  // padded per-16-col block stride (floats) in aggbd As/Ts: banks k*20%32 all-distinct

using s8v = __attribute__((ext_vector_type(8))) short;
using f4v = __attribute__((ext_vector_type(4))) float;
using h4v = __attribute__((ext_vector_type(4))) _Float16;
typedef unsigned int u32;

// async global->LDS, 16B per lane; LDS dest = wave-uniform base + lane*16 (m104),
// global src is PER-LANE (m173) -> swizzled layouts via pre-swizzled source address.
__device__ __forceinline__ void gload_lds16(const void* g, void* l) {
    __builtin_amdgcn_global_load_lds((const __attribute__((address_space(1))) u32*)g,
                                     (__attribute__((address_space(3))) u32*)l, 16, 0, 0);
}

// ---------------- CSR build ----------------
__global__ void k_deg(const int* __restrict__ dst, int* __restrict__ deg) {
    int e = blockIdx.x * 256 + threadIdx.x;
    if (e < NE) atomicAdd(&deg[dst[e]], 1);
}

__global__ __launch_bounds__(256) void k_bsum(const int* __restrict__ deg, int* __restrict__ bsum) {
    int idx = blockIdx.x * 256 + threadIdx.x;
    int v = (idx < NN) ? deg[idx] : 0;
#pragma unroll
    for (int off = 32; off; off >>= 1) v += __shfl_down(v, off, 64);
    __shared__ int ws[4];
    if ((threadIdx.x & 63) == 0) ws[threadIdx.x >> 6] = v;
    __syncthreads();
    if (threadIdx.x == 0) bsum[blockIdx.x] = ws[0] + ws[1] + ws[2] + ws[3];
}

__global__ __launch_bounds__(256) void k_bscan(const int* __restrict__ bsum, int* __restrict__ boffs) {
    __shared__ int s[256];
    int tid = threadIdx.x;
    int v = (tid < NB) ? bsum[tid] : 0;
    s[tid] = v;
    __syncthreads();
    for (int off = 1; off < 256; off <<= 1) {
        int t = (tid >= off) ? s[tid - off] : 0;
        __syncthreads();
        s[tid] += t;
        __syncthreads();
    }
    if (tid < NB) boffs[tid] = s[tid] - v;  // exclusive
}

__global__ __launch_bounds__(256) void k_offs(const int* __restrict__ deg,
                                              const int* __restrict__ boffs,
                                              int* __restrict__ offs) {
    __shared__ int s[256];
    int tid = threadIdx.x;
    int idx = blockIdx.x * 256 + tid;
    int v = (idx < NN) ? deg[idx] : 0;
    s[tid] = v;
    __syncthreads();
    for (int off = 1; off < 256; off <<= 1) {
        int t = (tid >= off) ? s[tid - off] : 0;
        __syncthreads();
        s[tid] += t;
        __syncthreads();
    }
    int incl = s[tid];
    if (idx < NN) offs[idx] = boffs[blockIdx.x] + incl - v;
    if (idx == NN - 1) offs[NN] = boffs[blockIdx.x] + incl;
}

__global__ void k_fill(const int* __restrict__ src, const int* __restrict__ dst,
                       const int* __restrict__ offs, int* __restrict__ cnt,
                       int* __restrict__ csr) {
    int e = blockIdx.x * 256 + threadIdx.x;
    if (e < NE) {
        int d = dst[e];
        int p = atomicAdd(&cnt[d], 1);
        csr[offs[d] + p] = src[e];
    }
}

// ---------------- helpers ----------------
__device__ __forceinline__ void bn_coefs(const float* st, const float* g, const float* be,
                                         int lane, float4& a4, float4& b4) {
    const float inv_n = 1.0f / (float)NN;
    float av[4], bv[4];
#pragma unroll
    for (int t = 0; t < 4; t++) {
        int c = lane * 4 + t;
        float mu = st[c] * inv_n;
        float var = st[FF + c] * inv_n - mu * mu;
        float a = g[c] * rsqrtf(var + BN_EPS);
        av[t] = a;
        bv[t] = be[c] - mu * a;
    }
    a4 = make_float4(av[0], av[1], av[2], av[3]);
    b4 = make_float4(bv[0], bv[1], bv[2], bv[3]);
}

// split fp32 -> bf16 hi + bf16 lo (round-to-nearest-even both)
__device__ __forceinline__ void f2bf2(float v, unsigned short& hi, unsigned short& lo) {
    unsigned u = __float_as_uint(v);
    unsigned r = u + 0x7fffu + ((u >> 16) & 1u);
    hi = (unsigned short)(r >> 16);
    float hf = __uint_as_float(((unsigned)hi) << 16);
    float lf = v - hf;
    unsigned u2 = __float_as_uint(lf);
    unsigned r2 = u2 + 0x7fffu + ((u2 >> 16) & 1u);
    lo = (unsigned short)(r2 >> 16);
}

__device__ __forceinline__ float4 h2f(h4v h) {
    return make_float4((float)h.x, (float)h.y, (float)h.z, (float)h.w);
}

// ---------------- fp32 -> fp16 one-shot convert of the input x ----------------
__global__ __launch_bounds__(256) void k_cvt(const float4* __restrict__ X, h4v* __restrict__ O) {
    int i = blockIdx.x * 256 + threadIdx.x;  // over NN*32
    if (i < NN * 32) {
        float4 v = X[i];
        h4v o;
        o.x = (_Float16)v.x; o.y = (_Float16)v.y;
        o.z = (_Float16)v.z; o.w = (_Float16)v.w;
        O[i] = o;
    }
}

// ---------------- weight prep: fp32 [l][k][n] -> bf16 hi/lo transposed [n][k] -------
__global__ __launch_bounds__(256) void k_wprep(const float* __restrict__ W1,
                                               const float* __restrict__ W2,
                                               unsigned short* __restrict__ out) {
    int idx = blockIdx.x * 256 + threadIdx.x;  // over 3*2*16384
    if (idx >= 3 * 2 * 16384) return;
    int l = idx / (2 * 16384);
    int rem = idx % (2 * 16384);
    int mat = rem >> 14;
    int e = rem & 16383;
    int n = e >> 7, k = e & 127;
    const float* W = (mat == 0) ? (W1 + (size_t)l * 16384) : (W2 + (size_t)l * 16384);
    float v = W[k * 128 + n];
    unsigned short hi, lo;
    f2bf2(v, hi, lo);
    unsigned short* o = out + (size_t)((l * 2 + mat) * 2) * 16384;
    o[n * 128 + k] = hi;
    o[16384 + n * 128 + k] = lo;
}

// ---------------- weight prep for h0: Wcat^T (slot 6) + blockdiag(W2)^T (slot 7) ---
__global__ __launch_bounds__(256) void k_wprep_h0(const float* __restrict__ W1,  // [K,F,d]
                                                  const float* __restrict__ W2,  // [K,d,d]
                                                  unsigned short* __restrict__ out) {
    int idx = blockIdx.x * 256 + threadIdx.x;  // over 2*16384
    if (idx >= 2 * 16384) return;
    int mat = idx >> 14;
    int e = idx & 16383;
    int n = e >> 7, k = e & 127;
    float v;
    if (mat == 0) {
        v = W1[(n >> 4) * (FF * DD) + k * DD + (n & 15)];
    } else {
        v = ((k >> 4) == (n >> 4)) ? W2[(n >> 4) * 256 + (k & 15) * DD + (n & 15)] : 0.f;
    }
    unsigned short hi, lo;
    f2bf2(v, hi, lo);
    unsigned short* o = out + (size_t)(6 + mat) * 32768;
    o[n * 128 + k] = hi;
    o[16384 + n * 128 + k] = lo;
}

// ---------------- aggregation (R6 layout + R8 index prefetch) ----------------
// 8 nodes/block, 32 lanes/node, h4v (8B)/lane. R8: CSR indices for batch i+1 load
// while batch i's data is being accumulated -> index-load latency off the critical
// path. Index reads up to 8 past e1 land in the adjacent ws region (discarded).
template <bool BN, bool RELU>
__global__ __launch_bounds__(256) void k_agg(const h4v* __restrict__ X,
                                             const int* __restrict__ offs,
                                             const int* __restrict__ csr,
                                             const float* __restrict__ st,
                                             const float* __restrict__ g,
                                             const float* __restrict__ be,
                                             unsigned short* __restrict__ Zhi,
                                             unsigned short* __restrict__ Zlo) {
    int grp = threadIdx.x >> 5;
    int lane = threadIdx.x & 31;
    int n = blockIdx.x * 8 + grp;

    float4 a4 = make_float4(1.f, 1.f, 1.f, 1.f);
    float4 b4 = make_float4(0.f, 0.f, 0.f, 0.f);
    if (BN) bn_coefs(st, g, be, lane, a4, b4);

    auto apply = [&](float4 v) -> float4 {
        if (BN) {
            v.x = fmaf(v.x, a4.x, b4.x);
            v.y = fmaf(v.y, a4.y, b4.y);
            v.z = fmaf(v.z, a4.z, b4.z);
            v.w = fmaf(v.w, a4.w, b4.w);
        }
        if (RELU) {
            v.x = fmaxf(v.x, 0.f);
            v.y = fmaxf(v.y, 0.f);
            v.z = fmaxf(v.z, 0.f);
            v.w = fmaxf(v.w, 0.f);
        }
        return v;
    };
    auto add4 = [](float4& a, float4 b) {
        a.x += b.x; a.y += b.y; a.z += b.z; a.w += b.w;
    };

    float4 acc = apply(h2f(X[(size_t)n * 32 + lane]));
    int e0 = offs[n], e1 = offs[n + 1];
    int e = e0;
    int s0, s1, s2, s3, s4, s5, s6, s7;
    if (e + 8 <= e1) {
        s0 = csr[e]; s1 = csr[e + 1]; s2 = csr[e + 2]; s3 = csr[e + 3];
        s4 = csr[e + 4]; s5 = csr[e + 5]; s6 = csr[e + 6]; s7 = csr[e + 7];
    }
    while (e + 8 <= e1) {
        h4v r0 = X[(size_t)s0 * 32 + lane];
        h4v r1 = X[(size_t)s1 * 32 + lane];
        h4v r2 = X[(size_t)s2 * 32 + lane];
        h4v r3 = X[(size_t)s3 * 32 + lane];
        h4v r4 = X[(size_t)s4 * 32 + lane];
        h4v r5 = X[(size_t)s5 * 32 + lane];
        h4v r6 = X[(size_t)s6 * 32 + lane];
        h4v r7 = X[(size_t)s7 * 32 + lane];
        e += 8;
        // prefetch next batch's indices under this batch's accumulate
        int t0 = csr[e], t1 = csr[e + 1], t2 = csr[e + 2], t3 = csr[e + 3];
        int t4 = csr[e + 4], t5 = csr[e + 5], t6 = csr[e + 6], t7 = csr[e + 7];
        float4 v0 = apply(h2f(r0));
        float4 v1 = apply(h2f(r1));
        float4 v2 = apply(h2f(r2));
        float4 v3 = apply(h2f(r3));
        float4 v4 = apply(h2f(r4));
        float4 v5 = apply(h2f(r5));
        float4 v6 = apply(h2f(r6));
        float4 v7 = apply(h2f(r7));
        add4(v0, v1); add4(v2, v3); add4(v4, v5); add4(v6, v7);
        add4(v0, v2); add4(v4, v6); add4(v0, v4); add4(acc, v0);
        s0 = t0; s1 = t1; s2 = t2; s3 = t3;
        s4 = t4; s5 = t5; s6 = t6; s7 = t7;
    }
    for (; e + 4 <= e1; e += 4) {
        int q0 = csr[e], q1 = csr[e + 1], q2 = csr[e + 2], q3 = csr[e + 3];
        float4 v0 = apply(h2f(X[(size_t)q0 * 32 + lane]));
        float4 v1 = apply(h2f(X[(size_t)q1 * 32 + lane]));
        float4 v2 = apply(h2f(X[(size_t)q2 * 32 + lane]));
        float4 v3 = apply(h2f(X[(size_t)q3 * 32 + lane]));
        add4(v0, v1); add4(v2, v3); add4(v0, v2); add4(acc, v0);
    }
    for (; e < e1; e++) {
        float4 v = apply(h2f(X[(size_t)csr[e] * 32 + lane]));
        add4(acc, v);
    }
    unsigned short h0, l0, h1, l1, h2, l2, h3, l3;
    f2bf2(acc.x, h0, l0); f2bf2(acc.y, h1, l1);
    f2bf2(acc.z, h2, l2); f2bf2(acc.w, h3, l3);
    *(ushort4*)&Zhi[(size_t)n * 128 + lane * 4] = make_ushort4(h0, h1, h2, h3);
    *(ushort4*)&Zlo[(size_t)n * 128 + lane * 4] = make_ushort4(l0, l1, l2, l3);
}

// ============ MFMA bf16x3 GEMM pair (R6 gload_lds + T3 overlap, unchanged) ============
__global__ __launch_bounds__(256) void gemm_mfma(const unsigned short* __restrict__ Zhi,
                                                 const unsigned short* __restrict__ Zlo,
                                                 const unsigned short* __restrict__ W1T,
                                                 const unsigned short* __restrict__ W2T,
                                                 const float* __restrict__ b1,
                                                 const float* __restrict__ b2,
                                                 _Float16* __restrict__ C,
                                                 float* __restrict__ stout) {
    __shared__ __align__(16) unsigned short Zs[16384];   // A/z hi+lo, [p][64][256B], 32KB
    __shared__ __align__(16) unsigned short Wch[16384];  // W chunk dbuf 2 x 16KB
    __shared__ float Sred[1024];                         // 4KB stats scratch
    int tid = threadIdx.x;
    int row0 = blockIdx.x * 64;
    int w = tid >> 6, lane = tid & 63, quad = lane >> 4, lid = lane & 15;

    // ---- per-thread W-stage source offsets (shorts, sans kc) ----
    int wsrc[4], wdst[4];
#pragma unroll
    for (int i = 0; i < 4; i++) {
        int L = (w * 4 + i) * 1024 + lane * 16;  // byte within 16KB chunk image
        int p = L >> 13, r13 = L & 8191;
        int npair = r13 >> 7, cc = r13 & 127;
        int ccp = cc ^ ((npair & 7) << 4);
        wsrc[i] = p * 16384 + (npair * 2 + (ccp >> 6)) * 128 + ((ccp & 63) >> 1);
        wdst[i] = (w * 4 + i) * 1024;            // wave-uniform LDS byte base
    }

    // ---- stage A hi/lo planes into Zs (global src pre-swizzled) ----
#pragma unroll
    for (int i = 0; i < 8; i++) {
        int L = (w * 8 + i) * 1024 + lane * 16;
        int p = L >> 14, r14 = L & 16383;
        int row = r14 >> 8, cb = r14 & 255;
        int cbp = cb ^ ((row & 7) << 4);
        int grow = row0 + row;
        if (grow >= NN) grow = NN - 1;
        const unsigned short* gs = (p ? Zlo : Zhi) + (size_t)grow * 128 + (cbp >> 1);
        gload_lds16(gs, (char*)Zs + (w * 8 + i) * 1024);
    }
    // ---- stage W1 chunk 0 into buf 0 ----
#pragma unroll
    for (int i = 0; i < 4; i++)
        gload_lds16(W1T + wsrc[i], (char*)Wch + wdst[i]);
    __syncthreads();

    // ---- per-thread read-address precompute ----
    int lr = w * 16 + lid;
    int swzr = (lr & 7) << 4;
    int abase = lr * 256;  // byte within plane 0 of Zs
    int boff[8];
#pragma unroll
    for (int n0 = 0; n0 < 8; n0++) {
        int nn = n0 * 16 + lid;
        int cc = ((nn & 1) << 6) | (quad << 4);
        boff[n0] = (nn >> 1) * 128 + (cc ^ (((nn >> 1) & 7) << 4));
    }

    f4v acc[8];
#pragma unroll
    for (int i = 0; i < 8; i++) acc[i] = 0;

    // ---- unified 8-chunk loop: g 0..3 = phase 1 (W1), 4..7 = phase 2 (W2) ----
    for (int g = 0; g < 8; ++g) {
        int buf = g & 1;
        if (g < 7) {  // issue next chunk's stage first (overlaps with compute below)
            const unsigned short* WT = (g + 1 < 4) ? W1T : W2T;
            int kcn = (g + 1) & 3;
#pragma unroll
            for (int i = 0; i < 4; i++)
                gload_lds16(WT + wsrc[i] + kcn * 32,
                            (char*)Wch + (buf ^ 1) * 16384 + wdst[i]);
        }
        int kc = g & 3;
        int aoff = (kc * 64 + quad * 16) ^ swzr;
        s8v ah = *(const s8v*)((const char*)Zs + abase + aoff);
        s8v al = *(const s8v*)((const char*)Zs + 16384 + abase + aoff);
        const char* wb = (const char*)Wch + buf * 16384;
#pragma unroll
        for (int n0 = 0; n0 < 8; n0++) {
            s8v bh = *(const s8v*)(wb + boff[n0]);
            s8v bl = *(const s8v*)(wb + 8192 + boff[n0]);
            acc[n0] = __builtin_amdgcn_mfma_f32_16x16x32_bf16(ah, bh, acc[n0], 0, 0, 0);
            acc[n0] = __builtin_amdgcn_mfma_f32_16x16x32_bf16(al, bh, acc[n0], 0, 0, 0);
            acc[n0] = __builtin_amdgcn_mfma_f32_16x16x32_bf16(ah, bl, acc[n0], 0, 0, 0);
        }
        if (g == 3) {
            // z = relu(acc+b1) -> overwrite Zs (wave-local rows), same swizzled layout
#pragma unroll
            for (int n0 = 0; n0 < 8; n0++) {
                int c = n0 * 16 + lid;
                float bb = b1[c];
#pragma unroll
                for (int rr = 0; rr < 4; rr++) {
                    int zr = w * 16 + quad * 4 + rr;
                    float z = fmaxf(acc[n0][rr] + bb, 0.f);
                    unsigned short h, lo2;
                    f2bf2(z, h, lo2);
                    int zb = zr * 256 + ((2 * c) ^ ((zr & 7) << 4));
                    *(unsigned short*)((char*)Zs + zb) = h;
                    *(unsigned short*)((char*)Zs + 16384 + zb) = lo2;
                }
                acc[n0] = 0;
            }
        }
        if (g < 7) __syncthreads();  // drains next-chunk stage; orders buffer reuse
    }

    // ---- epilogue: bias, fp16 store, stats (stats from fp32 register values) ----
#pragma unroll
    for (int n0 = 0; n0 < 8; n0++) {
        int c = n0 * 16 + lid;
        float bb = b2[c];
        float s = 0.f, q = 0.f;
#pragma unroll
        for (int rr = 0; rr < 4; rr++) {
            int grow = row0 + w * 16 + quad * 4 + rr;
            if (grow < NN) {
                float v = acc[n0][rr] + bb;
                C[(size_t)grow * 128 + c] = (_Float16)v;
                s += v;
                q += v * v;
            }
        }
        s += __shfl_xor(s, 16); s += __shfl_xor(s, 32);
        q += __shfl_xor(q, 16); q += __shfl_xor(q, 32);
        if (quad == 0) {
            Sred[w * 128 + c] = s;
            Sred[512 + w * 128 + c] = q;
        }
    }
    __syncthreads();
    if (tid < 128) {
        float s = Sred[tid] + Sred[128 + tid] + Sred[256 + tid] + Sred[384 + tid];
        float q = Sred[512 + tid] + Sred[640 + tid] + Sred[768 + tid] + Sred[896 + tid];
        atomicAdd(&stout[tid], s);
        atomicAdd(&stout[FF + tid], q);
    }
}

// ---------------- fused h1: agg (R6 layout + index prefetch) + block-diag MLP ------
__global__ __launch_bounds__(256) void k_aggbd(const h4v* __restrict__ X,
                                               const int* __restrict__ offs,
                                               const int* __restrict__ csr,
                                               const float* __restrict__ st,
                                               const float* __restrict__ g,
                                               const float* __restrict__ be,
                                               const float* __restrict__ W1,
                                               const float4* __restrict__ b1,
                                               const float* __restrict__ W2,
                                               const float4* __restrict__ b2,
                                               float4* __restrict__ C) {
    __shared__ float As[8][8 * BSTR];
    __shared__ float Ts[8][8 * BSTR];
    __shared__ float Ws1[KF * KSTR];
    __shared__ float Ws2[KF * KSTR];
    int grp = threadIdx.x >> 5, lane = threadIdx.x & 31;
    int n = blockIdx.x * 8 + grp;

    for (int l = threadIdx.x; l < KF * 256; l += 256) {
        int k = l >> 8, r = l & 255;
        Ws1[k * KSTR + r] = W1[l];
        Ws2[k * KSTR + r] = W2[l];
    }

    float4 a4, b4;
    bn_coefs(st, g, be, lane, a4, b4);
    auto apply = [&](float4 v) -> float4 {
        v.x = fmaxf(fmaf(v.x, a4.x, b4.x), 0.f);
        v.y = fmaxf(fmaf(v.y, a4.y, b4.y), 0.f);
        v.z = fmaxf(fmaf(v.z, a4.z, b4.z), 0.f);
        v.w = fmaxf(fmaf(v.w, a4.w, b4.w), 0.f);
        return v;
    };
    auto add4 = [](float4& a, float4 b) {
        a.x += b.x; a.y += b.y; a.z += b.z; a.w += b.w;
    };

    float4 acc = apply(h2f(X[(size_t)n * 32 + lane]));
    int e0 = offs[n], e1 = offs[n + 1];
    int e = e0;
    int s0, s1, s2, s3, s4, s5, s6, s7;
    if (e + 8 <= e1) {
        s0 = csr[e]; s1 = csr[e + 1]; s2 = csr[e + 2]; s3 = csr[e + 3];
        s4 = csr[e + 4]; s5 = csr[e + 5]; s6 = csr[e + 6]; s7 = csr[e + 7];
    }
    while (e + 8 <= e1) {
        h4v r0 = X[(size_t)s0 * 32 + lane];
        h4v r1 = X[(size_t)s1 * 32 + lane];
        h4v r2 = X[(size_t)s2 * 32 + lane];
        h4v r3 = X[(size_t)s3 * 32 + lane];
        h4v r4 = X[(size_t)s4 * 32 + lane];
        h4v r5 = X[(size_t)s5 * 32 + lane];
        h4v r6 = X[(size_t)s6 * 32 + lane];
        h4v r7 = X[(size_t)s7 * 32 + lane];
        e += 8;
        int t0 = csr[e], t1 = csr[e + 1], t2 = csr[e + 2], t3 = csr[e + 3];
        int t4 = csr[e + 4], t5 = csr[e + 5], t6 = csr[e + 6], t7 = csr[e + 7];
        float4 v0 = apply(h2f(r0));
        float4 v1 = apply(h2f(r1));
        float4 v2 = apply(h2f(r2));
        float4 v3 = apply(h2f(r3));
        float4 v4 = apply(h2f(r4));
        float4 v5 = apply(h2f(r5));
        float4 v6 = apply(h2f(r6));
        float4 v7 = apply(h2f(r7));
        add4(v0, v1); add4(v2, v3); add4(v4, v5); add4(v6, v7);
        add4(v0, v2); add4(v4, v6); add4(v0, v4); add4(acc, v0);
        s0 = t0; s1 = t1; s2 = t2; s3 = t3;
        s4 = t4; s5 = t5; s6 = t6; s7 = t7;
    }
    for (; e + 4 <= e1; e += 4) {
        int q0 = csr[e], q1 = csr[e + 1], q2 = csr[e + 2], q3 = csr[e + 3];
        float4 v0 = apply(h2f(X[(size_t)q0 * 32 + lane]));
        float4 v1 = apply(h2f(X[(size_t)q1 * 32 + lane]));
        float4 v2 = apply(h2f(X[(size_t)q2 * 32 + lane]));
        float4 v3 = apply(h2f(X[(size_t)q3 * 32 + lane]));
        add4(v0, v1); add4(v2, v3); add4(v0, v2); add4(acc, v0);
    }
    for (; e < e1; e++) {
        float4 v = apply(h2f(X[(size_t)csr[e] * 32 + lane]));
        add4(acc, v);
    }
    // store agg result (cols lane*4..+3) into padded layout
    *(float4*)&As[grp][(lane >> 2) * BSTR + (lane & 3) * 4] = acc;
    __syncthreads();

    int k = lane >> 2, jb = (lane & 3) * 4;
    float a[16];
    {
        const float4* As4 = (const float4*)&As[grp][k * BSTR];
        float4 a0 = As4[0], a1 = As4[1], a2 = As4[2], a3 = As4[3];
        a[0] = a0.x; a[1] = a0.y; a[2] = a0.z; a[3] = a0.w;
        a[4] = a1.x; a[5] = a1.y; a[6] = a1.z; a[7] = a1.w;
        a[8] = a2.x; a[9] = a2.y; a[10] = a2.z; a[11] = a2.w;
        a[12] = a3.x; a[13] = a3.y; a[14] = a3.z; a[15] = a3.w;
    }
    const float* wp1 = &Ws1[k * KSTR + jb];
    float4 t = b1[lane];
#pragma unroll
    for (int i = 0; i < 16; i++) {
        float4 wv = *(const float4*)&wp1[i * 16];
        t.x = fmaf(a[i], wv.x, t.x);
        t.y = fmaf(a[i], wv.y, t.y);
        t.z = fmaf(a[i], wv.z, t.z);
        t.w = fmaf(a[i], wv.w, t.w);
    }
    t.x = fmaxf(t.x, 0.f); t.y = fmaxf(t.y, 0.f);
    t.z = fmaxf(t.z, 0.f); t.w = fmaxf(t.w, 0.f);
    *(float4*)&Ts[grp][(lane >> 2) * BSTR + (lane & 3) * 4] = t;
    __syncthreads();

    float b[16];
    {
        const float4* Ts4 = (const float4*)&Ts[grp][k * BSTR];
        float4 a0 = Ts4[0], a1 = Ts4[1], a2 = Ts4[2], a3 = Ts4[3];
        b[0] = a0.x; b[1] = a0.y; b[2] = a0.z; b[3] = a0.w;
        b[4] = a1.x; b[5] = a1.y; b[6] = a1.z; b[7] = a1.w;
        b[8] = a2.x; b[9] = a2.y; b[10] = a2.z; b[11] = a2.w;
        b[12] = a3.x; b[13] = a3.y; b[14] = a3.z; b[15] = a3.w;
    }
    const float* wp2 = &Ws2[k * KSTR + jb];
    float4 acc2 = b2[lane];
#pragma unroll
    for (int i = 0; i < 16; i++) {
        float4 wv = *(const float4*)&wp2[i * 16];
        acc2.x = fmaf(b[i], wv.x, acc2.x);
        acc2.y = fmaf(b[i], wv.y, acc2.y);
        acc2.z = fmaf(b[i], wv.z, acc2.z);
        acc2.w = fmaf(b[i], wv.w, acc2.w);
    }
    C[(size_t)n * 32 + lane] = acc2;
}

// ---------------- BN stats (standalone, for k_aggbd output) ----------------
__global__ __launch_bounds__(256) void k_stats(const float* __restrict__ X,
                                               float* __restrict__ st, int nrows) {
    int c = threadIdx.x & 127;
    int half = threadIdx.x >> 7;
    int rpb = (nrows + gridDim.x - 1) / gridDim.x;
    int r0 = blockIdx.x * rpb;
    int r1 = min(r0 + rpb, nrows);
    float s = 0.f, sq = 0.f;
    for (int r = r0 + half; r < r1; r += 2) {
        float v = X[(size_t)r * FF + c];
        s += v;
        sq += v * v;
    }
    atomicAdd(&st[c], s);
    atomicAdd(&st[FF + c], sq);
}

// ---------------- pooling with fused final BN ----------------
__global__ __launch_bounds__(128) void k_pool(const float* __restrict__ X,
                                              const int* __restrict__ batch,
                                              const float* __restrict__ st,
                                              const float* __restrict__ g,
                                              const float* __restrict__ be,
                                              float* __restrict__ out) {
    int c = threadIdx.x;
    const float inv_n = 1.0f / (float)NN;
    float mu = st[c] * inv_n;
    float var = st[FF + c] * inv_n - mu * mu;
    float a = g[c] * rsqrtf(var + BN_EPS);
    float b = be[c] - mu * a;
    int chunk = (NN + gridDim.x - 1) / gridDim.x;
    int r0 = blockIdx.x * chunk;
    int r1 = min(r0 + chunk, NN);
    if (r0 >= r1) return;
    float acc = 0.f;
    int cnt = 0;
    int cur = batch[r0];
    for (int r = r0; r < r1; r++) {
        int bb = batch[r];
        if (bb != cur) {
            atomicAdd(&out[(size_t)cur * FF + c], fmaf(a, acc, b * (float)cnt));
            acc = 0.f;
            cnt = 0;
            cur = bb;
        }
        acc += X[(size_t)r * FF + c];
        cnt++;
    }
    atomicAdd(&out[(size_t)cur * FF + c], fmaf(a, acc, b * (float)cnt));
}

extern "C" void kernel_launch(void* const* d_in, const int* in_sizes, int n_in,
                              void* d_out, int out_size, void* d_ws, size_t ws_size,
                              hipStream_t stream) {
    const float* x = (const float*)d_in[0];
    const int* ei = (const int*)d_in[1];
    const int* src = ei;
    const int* dst = ei + NE;
    const int* batch = (const int*)d_in[2];
    const float* gc_W1 = (const float*)d_in[4];
    const float* gc_b1 = (const float*)d_in[5];
    const float* gc_W2 = (const float*)d_in[6];
    const float* gc_b2 = (const float*)d_in[7];
    const float* gc_g = (const float*)d_in[8];
    const float* gc_be = (const float*)d_in[9];
    const float* h0_W1 = (const float*)d_in[10];
    const float* h0_b1 = (const float*)d_in[11];
    const float* h0_W2 = (const float*)d_in[12];
    const float* h0_b2 = (const float*)d_in[13];
    const float* h0_g = (const float*)d_in[14];
    const float* h0_be = (const float*)d_in[15];
    const float* h1_W1 = (const float*)d_in[16];
    const float* h1_b1 = (const float*)d_in[17];
    const float* h1_W2 = (const float*)d_in[18];
    const float* h1_b2 = (const float*)d_in[19];
    const float* h1_g = (const float*)d_in[20];
    const float* h1_be = (const float*)d_in[21];

    const size_t NF = (size_t)NN * FF;
    float* P0 = (float*)d_ws;  // reused as two bf16 planes (Zhi, Zlo)
    float* P1 = P0 + NF;       // fp16 activation buffer (Hbuf) lives here
    float* P2 = P1 + NF;
    float* stats = P2 + NF;
    int* deg = (int*)(stats + 5 * 256);
    int* cnt = deg + NN;
    int* offs = cnt + NN;
    int* bsum = offs + (NN + 4);
    int* boffs = bsum + 256;
    int* csr = boffs + 256;
    unsigned short* wbf = (unsigned short*)(csr + NE);  // 8 slots x 32768 shorts

    unsigned short* Zhi = (unsigned short*)P0;
    unsigned short* Zlo = Zhi + NF;
    h4v* Hbuf = (h4v*)P1;  // fp16 activations, NN x 128 halves (NN*32 h4v)

    hipMemsetAsync(deg, 0, (size_t)2 * NN * sizeof(int), stream);
    hipMemsetAsync(stats, 0, 5 * 256 * sizeof(float), stream);
    hipMemsetAsync(d_out, 0, (size_t)GG * KF * DD * sizeof(float), stream);

    k_deg<<<(NE + 255) / 256, 256, 0, stream>>>(dst, deg);
    k_bsum<<<NB, 256, 0, stream>>>(deg, bsum);
    k_bscan<<<1, 256, 0, stream>>>(bsum, boffs);
    k_offs<<<NB, 256, 0, stream>>>(deg, boffs, offs);
    k_fill<<<(NE + 255) / 256, 256, 0, stream>>>(src, dst, offs, cnt, csr);
    k_wprep<<<(3 * 2 * 16384 + 255) / 256, 256, 0, stream>>>(gc_W1, gc_W2, wbf);
    k_wprep_h0<<<(2 * 16384 + 255) / 256, 256, 0, stream>>>(h0_W1, h0_W2, wbf);
    k_cvt<<<(NN * 32 + 255) / 256, 256, 0, stream>>>((const float4*)x, Hbuf);

    const int agg_grid = NN / 8;            // 6250
    const int gemm_grid = (NN + 63) / 64;   // 782

    // ---- GC layers: agg(bf16-plane out) + MFMA bf16x3 gemm pair (stats fused) ----
    k_agg<false, false><<<agg_grid, 256, 0, stream>>>(
        Hbuf, offs, csr, nullptr, nullptr, nullptr, Zhi, Zlo);
    gemm_mfma<<<gemm_grid, 256, 0, stream>>>(
        Zhi, Zlo, wbf + 0 * 32768, wbf + 1 * 32768, gc_b1, gc_b2, (_Float16*)Hbuf, stats);

    k_agg<true, true><<<agg_grid, 256, 0, stream>>>(
        Hbuf, offs, csr, stats, gc_g, gc_be, Zhi, Zlo);
    gemm_mfma<<<gemm_grid, 256, 0, stream>>>(
        Zhi, Zlo, wbf + 2 * 32768, wbf + 3 * 32768, gc_b1 + FF, gc_b2 + FF, (_Float16*)Hbuf,
        stats + 256);

    k_agg<true, true><<<agg_grid, 256, 0, stream>>>(
        Hbuf, offs, csr, stats + 256, gc_g + FF, gc_be + FF, Zhi, Zlo);
    gemm_mfma<<<gemm_grid, 256, 0, stream>>>(
        Zhi, Zlo, wbf + 4 * 32768, wbf + 5 * 32768, gc_b1 + 2 * FF, gc_b2 + 2 * FF,
        (_Float16*)Hbuf, stats + 512);

    // ---- head layer 0: agg (GC2 BN, no relu) + MFMA (Wcat + blockdiag) ----
    k_agg<true, false><<<agg_grid, 256, 0, stream>>>(
        Hbuf, offs, csr, stats + 512, gc_g + 2 * FF, gc_be + 2 * FF, Zhi, Zlo);
    gemm_mfma<<<gemm_grid, 256, 0, stream>>>(
        Zhi, Zlo, wbf + 6 * 32768, wbf + 7 * 32768, h0_b1, h0_b2, (_Float16*)Hbuf, stats + 768);

    // ---- head layer 1: fused agg(BN+relu) + double block-diag MLP ----
    k_aggbd<<<agg_grid, 256, 0, stream>>>(
        Hbuf, offs, csr, stats + 768, h0_g, h0_be,
        h1_W1, (const float4*)h1_b1, h1_W2, (const float4*)h1_b2, (float4*)P2);
    k_stats<<<256, 256, 0, stream>>>(P2, stats + 1024, NN);

    // ---- pool with fused final BN ----
    k_pool<<<512, 128, 0, stream>>>(P2, batch, stats + 1024, h1_g, h1_be, (float*)d_out);
}

// Round 9
// 575.974 us; speedup vs baseline: 1.1708x; 1.0739x over previous
//
#include <hip/hip_runtime.h>

#define NN 50000
#define NE 800000
#define FF 128
#define KF 8
#define DD 16
#define GG 512
#define BN_EPS 1e-5f
#define NB 196   // ceil(NN/256)
#define KSTR 264 // padded k-block stride for block-diag weights (flat staging)
#define BSTR 20  // padded per-16-col block stride (floats) in aggbd As/Ts: banks k*20%32 all-distinct

using s8v = __attribute__((ext_vector_type(8))) short;
using f4v = __attribute__((ext_vector_type(4))) float;
using h4v = __attribute__((ext_vector_type(4))) _Float16;
using h8v = __attribute__((ext_vector_type(8))) _Float16;
typedef unsigned int u32;

// async global->LDS, 16B per lane; LDS dest = wave-uniform base + lane*16 (m104),
// global src is PER-LANE (m173) -> swizzled layouts via pre-swizzled source address.
__device__ __forceinline__ void gload_lds16(const void* g, void* l) {
    __builtin_amdgcn_global_load_lds((const __attribute__((address_space(1))) u32*)g,
                                     (__attribute__((address_space(3))) u32*)l, 16, 0, 0);
}

// ---------------- CSR build ----------------
__global__ void k_deg(const int* __restrict__ dst, int* __restrict__ deg) {
    int e = blockIdx.x * 256 + threadIdx.x;
    if (e < NE) atomicAdd(&deg[dst[e]], 1);
}

__global__ __launch_bounds__(256) void k_bsum(const int* __restrict__ deg, int* __restrict__ bsum) {
    int idx = blockIdx.x * 256 + threadIdx.x;
    int v = (idx < NN) ? deg[idx] : 0;
#pragma unroll
    for (int off = 32; off; off >>= 1) v += __shfl_down(v, off, 64);
    __shared__ int ws[4];
    if ((threadIdx.x & 63) == 0) ws[threadIdx.x >> 6] = v;
    __syncthreads();
    if (threadIdx.x == 0) bsum[blockIdx.x] = ws[0] + ws[1] + ws[2] + ws[3];
}

__global__ __launch_bounds__(256) void k_bscan(const int* __restrict__ bsum, int* __restrict__ boffs) {
    __shared__ int s[256];
    int tid = threadIdx.x;
    int v = (tid < NB) ? bsum[tid] : 0;
    s[tid] = v;
    __syncthreads();
    for (int off = 1; off < 256; off <<= 1) {
        int t = (tid >= off) ? s[tid - off] : 0;
        __syncthreads();
        s[tid] += t;
        __syncthreads();
    }
    if (tid < NB) boffs[tid] = s[tid] - v;  // exclusive
}

__global__ __launch_bounds__(256) void k_offs(const int* __restrict__ deg,
                                              const int* __restrict__ boffs,
                                              int* __restrict__ offs) {
    __shared__ int s[256];
    int tid = threadIdx.x;
    int idx = blockIdx.x * 256 + tid;
    int v = (idx < NN) ? deg[idx] : 0;
    s[tid] = v;
    __syncthreads();
    for (int off = 1; off < 256; off <<= 1) {
        int t = (tid >= off) ? s[tid - off] : 0;
        __syncthreads();
        s[tid] += t;
        __syncthreads();
    }
    int incl = s[tid];
    if (idx < NN) offs[idx] = boffs[blockIdx.x] + incl - v;
    if (idx == NN - 1) offs[NN] = boffs[blockIdx.x] + incl;
}

__global__ void k_fill(const int* __restrict__ src, const int* __restrict__ dst,
                       const int* __restrict__ offs, int* __restrict__ cnt,
                       int* __restrict__ csr) {
    int e = blockIdx.x * 256 + threadIdx.x;
    if (e < NE) {
        int d = dst[e];
        int p = atomicAdd(&cnt[d], 1);
        csr[offs[d] + p] = src[e];
    }
}

// ---------------- helpers ----------------
__device__ __forceinline__ void bn_coefs(const float* st, const float* g, const float* be,
                                         int lane, float4& a4, float4& b4) {
    const float inv_n = 1.0f / (float)NN;
    float av[4], bv[4];
#pragma unroll
    for (int t = 0; t < 4; t++) {
        int c = lane * 4 + t;
        float mu = st[c] * inv_n;
        float var = st[FF + c] * inv_n - mu * mu;
        float a = g[c] * rsqrtf(var + BN_EPS);
        av[t] = a;
        bv[t] = be[c] - mu * a;
    }
    a4 = make_float4(av[0], av[1], av[2], av[3]);
    b4 = make_float4(bv[0], bv[1], bv[2], bv[3]);
}

__device__ __forceinline__ float4 h2f(h4v h) {
    return make_float4((float)h.x, (float)h.y, (float)h.z, (float)h.w);
}

// ---------------- fp32 -> fp16 one-shot convert of the input x ----------------
__global__ __launch_bounds__(256) void k_cvt(const float4* __restrict__ X, h4v* __restrict__ O) {
    int i = blockIdx.x * 256 + threadIdx.x;  // over NN*32
    if (i < NN * 32) {
        float4 v = X[i];
        h4v o;
        o.x = (_Float16)v.x; o.y = (_Float16)v.y;
        o.z = (_Float16)v.z; o.w = (_Float16)v.w;
        O[i] = o;
    }
}

// ---------------- weight prep: fp32 [l][k][n] -> fp16 W^T [n][k] (single plane) ----
__global__ __launch_bounds__(256) void k_wprep(const float* __restrict__ W1,
                                               const float* __restrict__ W2,
                                               unsigned short* __restrict__ out) {
    int idx = blockIdx.x * 256 + threadIdx.x;  // over 3*2*16384
    if (idx >= 3 * 2 * 16384) return;
    int l = idx / (2 * 16384);
    int rem = idx % (2 * 16384);
    int mat = rem >> 14;
    int e = rem & 16383;
    int n = e >> 7, k = e & 127;
    const float* W = (mat == 0) ? (W1 + (size_t)l * 16384) : (W2 + (size_t)l * 16384);
    float v = W[k * 128 + n];
    _Float16* o = (_Float16*)out + (size_t)(l * 2 + mat) * 16384;
    o[n * 128 + k] = (_Float16)v;
}

// ---------------- weight prep for h0: Wcat^T (slot 6) + blockdiag(W2)^T (slot 7) ---
__global__ __launch_bounds__(256) void k_wprep_h0(const float* __restrict__ W1,  // [K,F,d]
                                                  const float* __restrict__ W2,  // [K,d,d]
                                                  unsigned short* __restrict__ out) {
    int idx = blockIdx.x * 256 + threadIdx.x;  // over 2*16384
    if (idx >= 2 * 16384) return;
    int mat = idx >> 14;
    int e = idx & 16383;
    int n = e >> 7, k = e & 127;
    float v;
    if (mat == 0) {
        v = W1[(n >> 4) * (FF * DD) + k * DD + (n & 15)];
    } else {
        v = ((k >> 4) == (n >> 4)) ? W2[(n >> 4) * 256 + (k & 15) * DD + (n & 15)] : 0.f;
    }
    _Float16* o = (_Float16*)out + (size_t)(6 + mat) * 16384;
    o[n * 128 + k] = (_Float16)v;
}

// ---------------- aggregation (R8 gather + fp16 single-plane output) ----------------
template <bool BN, bool RELU>
__global__ __launch_bounds__(256) void k_agg(const h4v* __restrict__ X,
                                             const int* __restrict__ offs,
                                             const int* __restrict__ csr,
                                             const float* __restrict__ st,
                                             const float* __restrict__ g,
                                             const float* __restrict__ be,
                                             h4v* __restrict__ Zh) {
    int grp = threadIdx.x >> 5;
    int lane = threadIdx.x & 31;
    int n = blockIdx.x * 8 + grp;

    float4 a4 = make_float4(1.f, 1.f, 1.f, 1.f);
    float4 b4 = make_float4(0.f, 0.f, 0.f, 0.f);
    if (BN) bn_coefs(st, g, be, lane, a4, b4);

    auto apply = [&](float4 v) -> float4 {
        if (BN) {
            v.x = fmaf(v.x, a4.x, b4.x);
            v.y = fmaf(v.y, a4.y, b4.y);
            v.z = fmaf(v.z, a4.z, b4.z);
            v.w = fmaf(v.w, a4.w, b4.w);
        }
        if (RELU) {
            v.x = fmaxf(v.x, 0.f);
            v.y = fmaxf(v.y, 0.f);
            v.z = fmaxf(v.z, 0.f);
            v.w = fmaxf(v.w, 0.f);
        }
        return v;
    };
    auto add4 = [](float4& a, float4 b) {
        a.x += b.x; a.y += b.y; a.z += b.z; a.w += b.w;
    };

    float4 acc = apply(h2f(X[(size_t)n * 32 + lane]));
    int e0 = offs[n], e1 = offs[n + 1];
    int e = e0;
    int s0, s1, s2, s3, s4, s5, s6, s7;
    if (e + 8 <= e1) {
        s0 = csr[e]; s1 = csr[e + 1]; s2 = csr[e + 2]; s3 = csr[e + 3];
        s4 = csr[e + 4]; s5 = csr[e + 5]; s6 = csr[e + 6]; s7 = csr[e + 7];
    }
    while (e + 8 <= e1) {
        h4v r0 = X[(size_t)s0 * 32 + lane];
        h4v r1 = X[(size_t)s1 * 32 + lane];
        h4v r2 = X[(size_t)s2 * 32 + lane];
        h4v r3 = X[(size_t)s3 * 32 + lane];
        h4v r4 = X[(size_t)s4 * 32 + lane];
        h4v r5 = X[(size_t)s5 * 32 + lane];
        h4v r6 = X[(size_t)s6 * 32 + lane];
        h4v r7 = X[(size_t)s7 * 32 + lane];
        e += 8;
        // prefetch next batch's indices under this batch's accumulate
        int t0 = csr[e], t1 = csr[e + 1], t2 = csr[e + 2], t3 = csr[e + 3];
        int t4 = csr[e + 4], t5 = csr[e + 5], t6 = csr[e + 6], t7 = csr[e + 7];
        float4 v0 = apply(h2f(r0));
        float4 v1 = apply(h2f(r1));
        float4 v2 = apply(h2f(r2));
        float4 v3 = apply(h2f(r3));
        float4 v4 = apply(h2f(r4));
        float4 v5 = apply(h2f(r5));
        float4 v6 = apply(h2f(r6));
        float4 v7 = apply(h2f(r7));
        add4(v0, v1); add4(v2, v3); add4(v4, v5); add4(v6, v7);
        add4(v0, v2); add4(v4, v6); add4(v0, v4); add4(acc, v0);
        s0 = t0; s1 = t1; s2 = t2; s3 = t3;
        s4 = t4; s5 = t5; s6 = t6; s7 = t7;
    }
    for (; e + 4 <= e1; e += 4) {
        int q0 = csr[e], q1 = csr[e + 1], q2 = csr[e + 2], q3 = csr[e + 3];
        float4 v0 = apply(h2f(X[(size_t)q0 * 32 + lane]));
        float4 v1 = apply(h2f(X[(size_t)q1 * 32 + lane]));
        float4 v2 = apply(h2f(X[(size_t)q2 * 32 + lane]));
        float4 v3 = apply(h2f(X[(size_t)q3 * 32 + lane]));
        add4(v0, v1); add4(v2, v3); add4(v0, v2); add4(acc, v0);
    }
    for (; e < e1; e++) {
        float4 v = apply(h2f(X[(size_t)csr[e] * 32 + lane]));
        add4(acc, v);
    }
    h4v o;
    o.x = (_Float16)acc.x; o.y = (_Float16)acc.y;
    o.z = (_Float16)acc.z; o.w = (_Float16)acc.w;
    Zh[(size_t)n * 32 + lane] = o;
}

// ============ fp16 MFMA GEMM pair: C = relu(A@W1+b1)@W2 + b2, + stats ============
// R9: single fp16 plane for A/z and W -> mfma_f32_16x16x32_f16 (1 MFMA per tile vs
// bf16x3's 3). LDS: Zs 16KB (z overwrites A in place, wave-local rows) + Wch dbuf
// 16KB + Sred 4KB = 36KB -> 4 blocks/CU (2x R8's occupancy). Same proven XOR
// swizzles (one plane). fp32 accumulate + fp32 stats retained.
__global__ __launch_bounds__(256) void gemm_mfma(const _Float16* __restrict__ A,
                                                 const unsigned short* __restrict__ W1T,
                                                 const unsigned short* __restrict__ W2T,
                                                 const float* __restrict__ b1,
                                                 const float* __restrict__ b2,
                                                 _Float16* __restrict__ C,
                                                 float* __restrict__ stout) {
    __shared__ __align__(16) unsigned short Zs[8192];   // A/z fp16 [64][256B], 16KB
    __shared__ __align__(16) unsigned short Wch[8192];  // W chunk dbuf 2 x 8KB
    __shared__ float Sred[1024];                        // 4KB stats scratch
    int tid = threadIdx.x;
    int row0 = blockIdx.x * 64;
    int w = tid >> 6, lane = tid & 63, quad = lane >> 4, lid = lane & 15;

    // ---- per-thread W-stage source offsets (halfs, sans kc); 8KB chunk, 2/wave ----
    int wsrc[2], wdst[2];
#pragma unroll
    for (int i = 0; i < 2; i++) {
        int L = (w * 2 + i) * 1024 + lane * 16;  // byte within 8KB chunk image
        int npair = L >> 7, cc = L & 127;
        int ccp = cc ^ ((npair & 7) << 4);
        wsrc[i] = (npair * 2 + (ccp >> 6)) * 128 + ((ccp & 63) >> 1);
        wdst[i] = (w * 2 + i) * 1024;            // wave-uniform LDS byte base
    }

    // ---- stage A fp16 plane into Zs (global src pre-swizzled); 16KB, 4/wave ----
#pragma unroll
    for (int i = 0; i < 4; i++) {
        int L = (w * 4 + i) * 1024 + lane * 16;
        int row = L >> 8, cb = L & 255;
        int cbp = cb ^ ((row & 7) << 4);
        int grow = row0 + row;
        if (grow >= NN) grow = NN - 1;
        gload_lds16((const char*)A + (size_t)grow * 256 + cbp,
                    (char*)Zs + (w * 4 + i) * 1024);
    }
    // ---- stage W1 chunk 0 into buf 0 ----
#pragma unroll
    for (int i = 0; i < 2; i++)
        gload_lds16(W1T + wsrc[i], (char*)Wch + wdst[i]);
    __syncthreads();

    // ---- per-thread read-address precompute ----
    int lr = w * 16 + lid;
    int swzr = (lr & 7) << 4;
    int abase = lr * 256;  // byte within Zs
    int boff[8];
#pragma unroll
    for (int n0 = 0; n0 < 8; n0++) {
        int nn = n0 * 16 + lid;
        int cc = ((nn & 1) << 6) | (quad << 4);
        boff[n0] = (nn >> 1) * 128 + (cc ^ (((nn >> 1) & 7) << 4));
    }

    f4v acc[8];
#pragma unroll
    for (int i = 0; i < 8; i++) acc[i] = 0;

    // ---- unified 8-chunk loop: g 0..3 = phase 1 (W1), 4..7 = phase 2 (W2) ----
    for (int g = 0; g < 8; ++g) {
        int buf = g & 1;
        if (g < 7) {  // issue next chunk's stage first (overlaps with compute below)
            const unsigned short* WT = (g + 1 < 4) ? W1T : W2T;
            int kcn = (g + 1) & 3;
#pragma unroll
            for (int i = 0; i < 2; i++)
                gload_lds16(WT + wsrc[i] + kcn * 32,
                            (char*)Wch + (buf ^ 1) * 8192 + wdst[i]);
        }
        int kc = g & 3;
        int aoff = (kc * 64 + quad * 16) ^ swzr;
        h8v a = *(const h8v*)((const char*)Zs + abase + aoff);
        const char* wb = (const char*)Wch + buf * 8192;
#pragma unroll
        for (int n0 = 0; n0 < 8; n0++) {
            h8v b = *(const h8v*)(wb + boff[n0]);
            acc[n0] = __builtin_amdgcn_mfma_f32_16x16x32_f16(a, b, acc[n0], 0, 0, 0);
        }
        if (g == 3) {
            // z = relu(acc+b1) -> overwrite Zs (wave-local rows), same swizzled layout
#pragma unroll
            for (int n0 = 0; n0 < 8; n0++) {
                int c = n0 * 16 + lid;
                float bb = b1[c];
#pragma unroll
                for (int rr = 0; rr < 4; rr++) {
                    int zr = w * 16 + quad * 4 + rr;
                    float z = fmaxf(acc[n0][rr] + bb, 0.f);
                    int zb = zr * 256 + ((2 * c) ^ ((zr & 7) << 4));
                    *(_Float16*)((char*)Zs + zb) = (_Float16)z;
                }
                acc[n0] = 0;
            }
        }
        if (g < 7) __syncthreads();  // drains next-chunk stage; orders buffer reuse
    }

    // ---- epilogue: bias, fp16 store, stats (stats from fp32 register values) ----
#pragma unroll
    for (int n0 = 0; n0 < 8; n0++) {
        int c = n0 * 16 + lid;
        float bb = b2[c];
        float s = 0.f, q = 0.f;
#pragma unroll
        for (int rr = 0; rr < 4; rr++) {
            int grow = row0 + w * 16 + quad * 4 + rr;
            if (grow < NN) {
                float v = acc[n0][rr] + bb;
                C[(size_t)grow * 128 + c] = (_Float16)v;
                s += v;
                q += v * v;
            }
        }
        s += __shfl_xor(s, 16); s += __shfl_xor(s, 32);
        q += __shfl_xor(q, 16); q += __shfl_xor(q, 32);
        if (quad == 0) {
            Sred[w * 128 + c] = s;
            Sred[512 + w * 128 + c] = q;
        }
    }
    __syncthreads();
    if (tid < 128) {
        float s = Sred[tid] + Sred[128 + tid] + Sred[256 + tid] + Sred[384 + tid];
        float q = Sred[512 + tid] + Sred[640 + tid] + Sred[768 + tid] + Sred[896 + tid];
        atomicAdd(&stout[tid], s);
        atomicAdd(&stout[FF + tid], q);
    }
}

// ---------------- fused h1: agg (R8 layout + index prefetch) + block-diag MLP ------
__global__ __launch_bounds__(256) void k_aggbd(const h4v* __restrict__ X,
                                               const int* __restrict__ offs,
                                               const int* __restrict__ csr,
                                               const float* __restrict__ st,
                                               const float* __restrict__ g,
                                               const float* __restrict__ be,
                                               const float* __restrict__ W1,
                                               const float4* __restrict__ b1,
                                               const float* __restrict__ W2,
                                               const float4* __restrict__ b2,
                                               float4* __restrict__ C) {
    __shared__ float As[8][8 * BSTR];
    __shared__ float Ts[8][8 * BSTR];
    __shared__ float Ws1[KF * KSTR];
    __shared__ float Ws2[KF * KSTR];
    int grp = threadIdx.x >> 5, lane = threadIdx.x & 31;
    int n = blockIdx.x * 8 + grp;

    for (int l = threadIdx.x; l < KF * 256; l += 256) {
        int k = l >> 8, r = l & 255;
        Ws1[k * KSTR + r] = W1[l];
        Ws2[k * KSTR + r] = W2[l];
    }

    float4 a4, b4;
    bn_coefs(st, g, be, lane, a4, b4);
    auto apply = [&](float4 v) -> float4 {
        v.x = fmaxf(fmaf(v.x, a4.x, b4.x), 0.f);
        v.y = fmaxf(fmaf(v.y, a4.y, b4.y), 0.f);
        v.z = fmaxf(fmaf(v.z, a4.z, b4.z), 0.f);
        v.w = fmaxf(fmaf(v.w, a4.w, b4.w), 0.f);
        return v;
    };
    auto add4 = [](float4& a, float4 b) {
        a.x += b.x; a.y += b.y; a.z += b.z; a.w += b.w;
    };

    float4 acc = apply(h2f(X[(size_t)n * 32 + lane]));
    int e0 = offs[n], e1 = offs[n + 1];
    int e = e0;
    int s0, s1, s2, s3, s4, s5, s6, s7;
    if (e + 8 <= e1) {
        s0 = csr[e]; s1 = csr[e + 1]; s2 = csr[e + 2]; s3 = csr[e + 3];
        s4 = csr[e + 4]; s5 = csr[e + 5]; s6 = csr[e + 6]; s7 = csr[e + 7];
    }
    while (e + 8 <= e1) {
        h4v r0 = X[(size_t)s0 * 32 + lane];
        h4v r1 = X[(size_t)s1 * 32 + lane];
        h4v r2 = X[(size_t)s2 * 32 + lane];
        h4v r3 = X[(size_t)s3 * 32 + lane];
        h4v r4 = X[(size_t)s4 * 32 + lane];
        h4v r5 = X[(size_t)s5 * 32 + lane];
        h4v r6 = X[(size_t)s6 * 32 + lane];
        h4v r7 = X[(size_t)s7 * 32 + lane];
        e += 8;
        int t0 = csr[e], t1 = csr[e + 1], t2 = csr[e + 2], t3 = csr[e + 3];
        int t4 = csr[e + 4], t5 = csr[e + 5], t6 = csr[e + 6], t7 = csr[e + 7];
        float4 v0 = apply(h2f(r0));
        float4 v1 = apply(h2f(r1));
        float4 v2 = apply(h2f(r2));
        float4 v3 = apply(h2f(r3));
        float4 v4 = apply(h2f(r4));
        float4 v5 = apply(h2f(r5));
        float4 v6 = apply(h2f(r6));
        float4 v7 = apply(h2f(r7));
        add4(v0, v1); add4(v2, v3); add4(v4, v5); add4(v6, v7);
        add4(v0, v2); add4(v4, v6); add4(v0, v4); add4(acc, v0);
        s0 = t0; s1 = t1; s2 = t2; s3 = t3;
        s4 = t4; s5 = t5; s6 = t6; s7 = t7;
    }
    for (; e + 4 <= e1; e += 4) {
        int q0 = csr[e], q1 = csr[e + 1], q2 = csr[e + 2], q3 = csr[e + 3];
        float4 v0 = apply(h2f(X[(size_t)q0 * 32 + lane]));
        float4 v1 = apply(h2f(X[(size_t)q1 * 32 + lane]));
        float4 v2 = apply(h2f(X[(size_t)q2 * 32 + lane]));
        float4 v3 = apply(h2f(X[(size_t)q3 * 32 + lane]));
        add4(v0, v1); add4(v2, v3); add4(v0, v2); add4(acc, v0);
    }
    for (; e < e1; e++) {
        float4 v = apply(h2f(X[(size_t)csr[e] * 32 + lane]));
        add4(acc, v);
    }
    // store agg result (cols lane*4..+3) into padded layout
    *(float4*)&As[grp][(lane >> 2) * BSTR + (lane & 3) * 4] = acc;
    __syncthreads();

    int k = lane >> 2, jb = (lane & 3) * 4;
    float a[16];
    {
        const float4* As4 = (const float4*)&As[grp][k * BSTR];
        float4 a0 = As4[0], a1 = As4[1], a2 = As4[2], a3 = As4[3];
        a[0] = a0.x; a[1] = a0.y; a[2] = a0.z; a[3] = a0.w;
        a[4] = a1.x; a[5] = a1.y; a[6] = a1.z; a[7] = a1.w;
        a[8] = a2.x; a[9] = a2.y; a[10] = a2.z; a[11] = a2.w;
        a[12] = a3.x; a[13] = a3.y; a[14] = a3.z; a[15] = a3.w;
    }
    const float* wp1 = &Ws1[k * KSTR + jb];
    float4 t = b1[lane];
#pragma unroll
    for (int i = 0; i < 16; i++) {
        float4 wv = *(const float4*)&wp1[i * 16];
        t.x = fmaf(a[i], wv.x, t.x);
        t.y = fmaf(a[i], wv.y, t.y);
        t.z = fmaf(a[i], wv.z, t.z);
        t.w = fmaf(a[i], wv.w, t.w);
    }
    t.x = fmaxf(t.x, 0.f); t.y = fmaxf(t.y, 0.f);
    t.z = fmaxf(t.z, 0.f); t.w = fmaxf(t.w, 0.f);
    *(float4*)&Ts[grp][(lane >> 2) * BSTR + (lane & 3) * 4] = t;
    __syncthreads();

    float b[16];
    {
        const float4* Ts4 = (const float4*)&Ts[grp][k * BSTR];
        float4 a0 = Ts4[0], a1 = Ts4[1], a2 = Ts4[2], a3 = Ts4[3];
        b[0] = a0.x; b[1] = a0.y; b[2] = a0.z; b[3] = a0.w;
        b[4] = a1.x; b[5] = a1.y; b[6] = a1.z; b[7] = a1.w;
        b[8] = a2.x; b[9] = a2.y; b[10] = a2.z; b[11] = a2.w;
        b[12] = a3.x; b[13] = a3.y; b[14] = a3.z; b[15] = a3.w;
    }
    const float* wp2 = &Ws2[k * KSTR + jb];
    float4 acc2 = b2[lane];
#pragma unroll
    for (int i = 0; i < 16; i++) {
        float4 wv = *(const float4*)&wp2[i * 16];
        acc2.x = fmaf(b[i], wv.x, acc2.x);
        acc2.y = fmaf(b[i], wv.y, acc2.y);
        acc2.z = fmaf(b[i], wv.z, acc2.z);
        acc2.w = fmaf(b[i], wv.w, acc2.w);
    }
    C[(size_t)n * 32 + lane] = acc2;
}

// ---------------- BN stats (standalone, for k_aggbd output) ----------------
__global__ __launch_bounds__(256) void k_stats(const float* __restrict__ X,
                                               float* __restrict__ st, int nrows) {
    int c = threadIdx.x & 127;
    int half = threadIdx.x >> 7;
    int rpb = (nrows + gridDim.x - 1) / gridDim.x;
    int r0 = blockIdx.x * rpb;
    int r1 = min(r0 + rpb, nrows);
    float s = 0.f, sq = 0.f;
    for (int r = r0 + half; r < r1; r += 2) {
        float v = X[(size_t)r * FF + c];
        s += v;
        sq += v * v;
    }
    atomicAdd(&st[c], s);
    atomicAdd(&st[FF + c], sq);
}

// ---------------- pooling with fused final BN ----------------
__global__ __launch_bounds__(128) void k_pool(const float* __restrict__ X,
                                              const int* __restrict__ batch,
                                              const float* __restrict__ st,
                                              const float* __restrict__ g,
                                              const float* __restrict__ be,
                                              float* __restrict__ out) {
    int c = threadIdx.x;
    const float inv_n = 1.0f / (float)NN;
    float mu = st[c] * inv_n;
    float var = st[FF + c] * inv_n - mu * mu;
    float a = g[c] * rsqrtf(var + BN_EPS);
    float b = be[c] - mu * a;
    int chunk = (NN + gridDim.x - 1) / gridDim.x;
    int r0 = blockIdx.x * chunk;
    int r1 = min(r0 + chunk, NN);
    if (r0 >= r1) return;
    float acc = 0.f;
    int cnt = 0;
    int cur = batch[r0];
    for (int r = r0; r < r1; r++) {
        int bb = batch[r];
        if (bb != cur) {
            atomicAdd(&out[(size_t)cur * FF + c], fmaf(a, acc, b * (float)cnt));
            acc = 0.f;
            cnt = 0;
            cur = bb;
        }
        acc += X[(size_t)r * FF + c];
        cnt++;
    }
    atomicAdd(&out[(size_t)cur * FF + c], fmaf(a, acc, b * (float)cnt));
}

extern "C" void kernel_launch(void* const* d_in, const int* in_sizes, int n_in,
                              void* d_out, int out_size, void* d_ws, size_t ws_size,
                              hipStream_t stream) {
    const float* x = (const float*)d_in[0];
    const int* ei = (const int*)d_in[1];
    const int* src = ei;
    const int* dst = ei + NE;
    const int* batch = (const int*)d_in[2];
    const float* gc_W1 = (const float*)d_in[4];
    const float* gc_b1 = (const float*)d_in[5];
    const float* gc_W2 = (const float*)d_in[6];
    const float* gc_b2 = (const float*)d_in[7];
    const float* gc_g = (const float*)d_in[8];
    const float* gc_be = (const float*)d_in[9];
    const float* h0_W1 = (const float*)d_in[10];
    const float* h0_b1 = (const float*)d_in[11];
    const float* h0_W2 = (const float*)d_in[12];
    const float* h0_b2 = (const float*)d_in[13];
    const float* h0_g = (const float*)d_in[14];
    const float* h0_be = (const float*)d_in[15];
    const float* h1_W1 = (const float*)d_in[16];
    const float* h1_b1 = (const float*)d_in[17];
    const float* h1_W2 = (const float*)d_in[18];
    const float* h1_b2 = (const float*)d_in[19];
    const float* h1_g = (const float*)d_in[20];
    const float* h1_be = (const float*)d_in[21];

    const size_t NF = (size_t)NN * FF;
    float* P0 = (float*)d_ws;  // Zh fp16 plane (k_agg output / gemm A input)
    float* P1 = P0 + NF;       // Hbuf fp16 (gemm C output / gather input)
    float* P2 = P1 + NF;
    float* stats = P2 + NF;
    int* deg = (int*)(stats + 5 * 256);
    int* cnt = deg + NN;
    int* offs = cnt + NN;
    int* bsum = offs + (NN + 4);
    int* boffs = bsum + 256;
    int* csr = boffs + 256;
    unsigned short* wbf = (unsigned short*)(csr + NE);  // 8 slots x 16384 fp16

    h4v* Zh = (h4v*)P0;    // fp16 agg output, NN x 128
    h4v* Hbuf = (h4v*)P1;  // fp16 activations, NN x 128

    hipMemsetAsync(deg, 0, (size_t)2 * NN * sizeof(int), stream);
    hipMemsetAsync(stats, 0, 5 * 256 * sizeof(float), stream);
    hipMemsetAsync(d_out, 0, (size_t)GG * KF * DD * sizeof(float), stream);

    k_deg<<<(NE + 255) / 256, 256, 0, stream>>>(dst, deg);
    k_bsum<<<NB, 256, 0, stream>>>(deg, bsum);
    k_bscan<<<1, 256, 0, stream>>>(bsum, boffs);
    k_offs<<<NB, 256, 0, stream>>>(deg, boffs, offs);
    k_fill<<<(NE + 255) / 256, 256, 0, stream>>>(src, dst, offs, cnt, csr);
    k_wprep<<<(3 * 2 * 16384 + 255) / 256, 256, 0, stream>>>(gc_W1, gc_W2, wbf);
    k_wprep_h0<<<(2 * 16384 + 255) / 256, 256, 0, stream>>>(h0_W1, h0_W2, wbf);
    k_cvt<<<(NN * 32 + 255) / 256, 256, 0, stream>>>((const float4*)x, Hbuf);

    const int agg_grid = NN / 8;            // 6250
    const int gemm_grid = (NN + 63) / 64;   // 782

    // ---- GC layers: agg(fp16 out) + fp16 MFMA gemm pair (stats fused) ----
    k_agg<false, false><<<agg_grid, 256, 0, stream>>>(
        Hbuf, offs, csr, nullptr, nullptr, nullptr, Zh);
    gemm_mfma<<<gemm_grid, 256, 0, stream>>>(
        (const _Float16*)Zh, wbf + 0 * 16384, wbf + 1 * 16384, gc_b1, gc_b2,
        (_Float16*)Hbuf, stats);

    k_agg<true, true><<<agg_grid, 256, 0, stream>>>(
        Hbuf, offs, csr, stats, gc_g, gc_be, Zh);
    gemm_mfma<<<gemm_grid, 256, 0, stream>>>(
        (const _Float16*)Zh, wbf + 2 * 16384, wbf + 3 * 16384, gc_b1 + FF, gc_b2 + FF,
        (_Float16*)Hbuf, stats + 256);

    k_agg<true, true><<<agg_grid, 256, 0, stream>>>(
        Hbuf, offs, csr, stats + 256, gc_g + FF, gc_be + FF, Zh);
    gemm_mfma<<<gemm_grid, 256, 0, stream>>>(
        (const _Float16*)Zh, wbf + 4 * 16384, wbf + 5 * 16384, gc_b1 + 2 * FF, gc_b2 + 2 * FF,
        (_Float16*)Hbuf, stats + 512);

    // ---- head layer 0: agg (GC2 BN, no relu) + fp16 MFMA (Wcat + blockdiag) ----
    k_agg<true, false><<<agg_grid, 256, 0, stream>>>(
        Hbuf, offs, csr, stats + 512, gc_g + 2 * FF, gc_be + 2 * FF, Zh);
    gemm_mfma<<<gemm_grid, 256, 0, stream>>>(
        (const _Float16*)Zh, wbf + 6 * 16384, wbf + 7 * 16384, h0_b1, h0_b2,
        (_Float16*)Hbuf, stats + 768);

    // ---- head layer 1: fused agg(BN+relu) + double block-diag MLP ----
    k_aggbd<<<agg_grid, 256, 0, stream>>>(
        Hbuf, offs, csr, stats + 768, h0_g, h0_be,
        h1_W1, (const float4*)h1_b1, h1_W2, (const float4*)h1_b2, (float4*)P2);
    k_stats<<<256, 256, 0, stream>>>(P2, stats + 1024, NN);

    // ---- pool with fused final BN ----
    k_pool<<<512, 128, 0, stream>>>(P2, batch, stats + 1024, h1_g, h1_be, (float*)d_out);
}